// Round 5
// baseline (263.927 us; speedup 1.0000x reference)
//
#include <hip/hip_runtime.h>

typedef _Float16 half8 __attribute__((ext_vector_type(8)));
typedef _Float16 half4 __attribute__((ext_vector_type(4)));
typedef _Float16 half2v __attribute__((ext_vector_type(2)));
typedef float floatx4 __attribute__((ext_vector_type(4)));
typedef unsigned int uint2v __attribute__((ext_vector_type(2)));
typedef unsigned int uint4v __attribute__((ext_vector_type(4)));

__device__ __forceinline__ void gl_lds16(const _Float16* g, _Float16* l) {
    __builtin_amdgcn_global_load_lds(
        (const __attribute__((address_space(1))) void*)g,
        (__attribute__((address_space(3))) void*)l, 16, 0, 0);
}

__device__ __forceinline__ half2v cvt_pk(float a, float b) {
    return __builtin_bit_cast(half2v, __builtin_amdgcn_cvt_pkrtz(a, b));
}

__device__ __forceinline__ half2v rcp2(half2v d) {
#if __has_builtin(__builtin_amdgcn_rcph)
    half2v r;
    r[0] = __builtin_amdgcn_rcph(d[0]);
    r[1] = __builtin_amdgcn_rcph(d[1]);
    return r;
#else
    half2v r;
    r[0] = (_Float16)__builtin_amdgcn_rcpf((float)d[0]);
    r[1] = (_Float16)__builtin_amdgcn_rcpf((float)d[1]);
    return r;
#endif
}

__device__ __forceinline__ float dot2acc(half2v a, float acc) {
#if __has_builtin(__builtin_amdgcn_fdot2)
    const half2v one = {(_Float16)1.0f, (_Float16)1.0f};
    return __builtin_amdgcn_fdot2(a, one, acc, false);
#else
    return acc + (float)a[0] + (float)a[1];
#endif
}

// concat 4 packed half2 (each one dword) into a half8 — no element inserts
__device__ __forceinline__ half8 from4(half2v a, half2v b, half2v c, half2v d) {
    uint4v u = {__builtin_bit_cast(unsigned int, a), __builtin_bit_cast(unsigned int, b),
                __builtin_bit_cast(unsigned int, c), __builtin_bit_cast(unsigned int, d)};
    return __builtin_bit_cast(half8, u);
}

// concat two half4 (two dword-pairs) into a half8 — no element inserts
__device__ __forceinline__ half8 from_lohi(half4 lo, half4 hi) {
    uint2v l = __builtin_bit_cast(uint2v, lo);
    uint2v h = __builtin_bit_cast(uint2v, hi);
    uint4v u = {l[0], l[1], h[0], h[1]};
    return __builtin_bit_cast(half8, u);
}

// ---------------- fp32 -> fp16 convert: x and w_qkv fused (runs BEFORE gemm_qkv) -
__global__ __launch_bounds__(256) void cvt_xw(const floatx4* __restrict__ x,
                                              const floatx4* __restrict__ wq,
                                              half4* __restrict__ xh,
                                              half4* __restrict__ wqh) {
    int i = blockIdx.x * 256 + threadIdx.x;   // 0..1835007
    floatx4 v;
    half4 h;
    if (i < 1048576) {
        v = x[i];
#pragma unroll
        for (int j = 0; j < 4; ++j) h[j] = (_Float16)v[j];
        xh[i] = h;
    } else {
        int j4 = i - 1048576;
        v = wq[j4];
#pragma unroll
        for (int j = 0; j < 4; ++j) h[j] = (_Float16)v[j];
        wqh[j4] = h;
    }
}

// wout cvt — MUST run after gemm_qkv (woh aliases wqh)
__global__ __launch_bounds__(256) void cvt_f32_f16(const floatx4* __restrict__ in,
                                                   half4* __restrict__ out, int n4) {
    int i = blockIdx.x * 256 + threadIdx.x;
    if (i >= n4) return;
    floatx4 v = in[i];
    half4 h;
#pragma unroll
    for (int j = 0; j < 4; ++j) h[j] = (_Float16)v[j];
    out[i] = h;
}

// ---------------- GEMM1: qkv = xh @ wqh^T -> head-major q/k/vt (fp16 in/out) -----
// M=4096, N=3072, K=1024. 128x128 tile, BK=32, 256 thr, DMA staging.
__global__ __launch_bounds__(256) void gemm_qkv(const _Float16* __restrict__ A,
                                                const _Float16* __restrict__ B,
                                                _Float16* __restrict__ qh,
                                                _Float16* __restrict__ kh,
                                                _Float16* __restrict__ vth) {
    const int K = 1024;
    __shared__ _Float16 SH[128 * 68];   // As 8KB | Bs 8KB; epilogue 128x68
    _Float16* As = SH;
    _Float16* Bs = SH + 4096;
    const int t = threadIdx.x;
    const int lane = t & 63, w = t >> 6;
    const int l15 = lane & 15, quad = lane >> 4;
    const int wm = w >> 1, wn = w & 1;
    const int m0 = blockIdx.y * 128, n0 = blockIdx.x * 128;

    floatx4 acc[4][4];
    const floatx4 zf = {0.f, 0.f, 0.f, 0.f};
#pragma unroll
    for (int i = 0; i < 4; ++i)
#pragma unroll
        for (int j = 0; j < 4; ++j) acc[i][j] = zf;

    for (int kt = 0; kt < K; kt += 32) {
        __syncthreads();
#pragma unroll
        for (int it = 0; it < 2; ++it) {    // 512 chunks of 16B per matrix
            int cc = it * 256 + t;
            int row = cc >> 2, kc = cc & 3;
            gl_lds16(&A[(size_t)(m0 + row) * K + kt + kc * 8], &As[cc * 8]);
            gl_lds16(&B[(size_t)(n0 + row) * K + kt + kc * 8], &Bs[cc * 8]);
        }
        __syncthreads();
        half8 af[4], bfr[4];
#pragma unroll
        for (int i = 0; i < 4; ++i)
            af[i] = *(const half8*)&As[(wm * 64 + i * 16 + l15) * 32 + quad * 8];
#pragma unroll
        for (int i = 0; i < 4; ++i)
            bfr[i] = *(const half8*)&Bs[(wn * 64 + i * 16 + l15) * 32 + quad * 8];
#pragma unroll
        for (int mi = 0; mi < 4; ++mi)
#pragma unroll
            for (int ni = 0; ni < 4; ++ni)
                acc[mi][ni] = __builtin_amdgcn_mfma_f32_16x16x32_f16(af[mi], bfr[ni],
                                                                     acc[mi][ni], 0, 0, 0);
    }

    // ---- epilogue: two 128x64 col-halves staged through LDS, coalesced writes ----
    const int b = m0 >> 11, s0 = m0 & 2047;
#pragma unroll
    for (int hf = 0; hf < 2; ++hf) {
        __syncthreads();
        if (wn == hf) {
#pragma unroll
            for (int mi = 0; mi < 4; ++mi)
#pragma unroll
                for (int ni = 0; ni < 4; ++ni)
#pragma unroll
                    for (int r = 0; r < 4; ++r)
                        SH[(wm * 64 + mi * 16 + quad * 4 + r) * 68 + ni * 16 + l15] =
                            (_Float16)acc[mi][ni][r];
        }
        __syncthreads();
        const int cbase = n0 + hf * 64;
        if (n0 < 2048) {
            const int hh = (cbase & 1023) >> 6;
            _Float16* dst = (n0 < 1024 ? qh : kh) + (size_t)((b << 4) | hh) * 131072;
#pragma unroll
            for (int it = 0; it < 4; ++it) {
                int cc = it * 256 + t;
                int r = cc >> 3, c8 = cc & 7;
                half4 lo = *(const half4*)&SH[r * 68 + c8 * 8];
                half4 hi = *(const half4*)&SH[r * 68 + c8 * 8 + 4];
                *(half8*)&dst[(size_t)(s0 + r) * 64 + c8 * 8] = from_lohi(lo, hi);
            }
        } else {
            const int hh = (cbase - 2048) >> 6;
            _Float16* dst = vth + (size_t)((b << 4) | hh) * 131072;
#pragma unroll
            for (int it = 0; it < 4; ++it) {
                int cc = it * 256 + t;
                int d = cc >> 4, s8 = cc & 15;
                half8 v;
#pragma unroll
                for (int j = 0; j < 8; ++j) v[j] = SH[(s8 * 8 + j) * 68 + d];
                *(half8*)&dst[(size_t)d * 2048 + s0 + s8 * 8] = v;
            }
        }
    }
}

// ---------------- GEMM2: out = aoh @ woh^T + b_out -> fp32 -----------------------
// M=4096, N=1024, K=1024. 64x128 tile, BK=32, 256 thr, DMA staging.
__global__ __launch_bounds__(256) void gemm_out(const _Float16* __restrict__ A,
                                                const _Float16* __restrict__ B,
                                                float* __restrict__ C,
                                                const float* __restrict__ bias) {
    const int K = 1024, N = 1024;
    __shared__ _Float16 SH[6144];   // As 64x32 (4KB) | Bs 128x32 (8KB)
    _Float16* As = SH;
    _Float16* Bs = SH + 2048;
    const int t = threadIdx.x;
    const int lane = t & 63, w = t >> 6;
    const int l15 = lane & 15, quad = lane >> 4;
    const int wm = w >> 1, wn = w & 1;
    const int m0 = blockIdx.y * 64, n0 = blockIdx.x * 128;

    floatx4 acc[2][4];
    const floatx4 zf = {0.f, 0.f, 0.f, 0.f};
#pragma unroll
    for (int i = 0; i < 2; ++i)
#pragma unroll
        for (int j = 0; j < 4; ++j) acc[i][j] = zf;

    for (int kt = 0; kt < K; kt += 32) {
        __syncthreads();
        {   // A: 256 chunks of 16B
            int row = t >> 2, kc = t & 3;
            gl_lds16(&A[(size_t)(m0 + row) * K + kt + kc * 8], &As[t * 8]);
        }
#pragma unroll
        for (int it = 0; it < 2; ++it) {    // B: 512 chunks of 16B
            int cc = it * 256 + t;
            int row = cc >> 2, kc = cc & 3;
            gl_lds16(&B[(size_t)(n0 + row) * K + kt + kc * 8], &Bs[cc * 8]);
        }
        __syncthreads();
        half8 af[2], bfr[4];
#pragma unroll
        for (int i = 0; i < 2; ++i)
            af[i] = *(const half8*)&As[(wm * 32 + i * 16 + l15) * 32 + quad * 8];
#pragma unroll
        for (int i = 0; i < 4; ++i)
            bfr[i] = *(const half8*)&Bs[(wn * 64 + i * 16 + l15) * 32 + quad * 8];
#pragma unroll
        for (int mi = 0; mi < 2; ++mi)
#pragma unroll
            for (int ni = 0; ni < 4; ++ni)
                acc[mi][ni] = __builtin_amdgcn_mfma_f32_16x16x32_f16(af[mi], bfr[ni],
                                                                     acc[mi][ni], 0, 0, 0);
    }

#pragma unroll
    for (int mi = 0; mi < 2; ++mi) {
#pragma unroll
        for (int ni = 0; ni < 4; ++ni) {
            int col = n0 + wn * 64 + ni * 16 + l15;
            float bv = bias[col];
#pragma unroll
            for (int r = 0; r < 4; ++r) {
                int row = m0 + wm * 32 + mi * 16 + quad * 4 + r;
                C[(size_t)row * N + col] = acc[mi][ni][r] + bv;
            }
        }
    }
}

// ---------------- fused two-pass stablemax attention (split-K, 4 waves) ----------
// R4 RESUBMIT (round-4 bench was an infra failure: "container failed twice";
// kernel re-audited: uniform barriers, in-bounds K ping-pong (max 131072 halfs,
// guarded prefetches), LDS layout within 32KB, wave-uniform DMA dests).
// K never touches LDS. K fragments are consumed in natural MFMA layout, so
// each lane reads its 16B fragment straight from global (dense 2KB/wave blocks,
// L1/L2-served; the 2 qg-waves re-read the same lines -> L1 hits). Pass 1 is
// BARRIER-FREE: K streams global->reg->MFMA with 2-deep ping-pong prefetch; pure
// TLP hiding across 16 waves/CU. Pass 2 stages only V in LDS (8KB/tile DMA vs
// 16KB), K global->reg prefetched under poly+PV. This removes the ds_read_b128
// K traffic that R1-R3 showed to be the saturated-pipe cost (LDS ~83% busy,
// conflicts invariant at 4.29M under swizzle changes => intrinsic to K b128).
// Split-K layout kept from R3: block = 64 q-rows, wave (qg,kg) owns 32q x 32k;
// cross-wave combine once per block (rmax / rsum+O) through LDS scratch.
// Q pre-scaled by 0.125; s3 in packed fp16; xm baked into pass-2 MFMA C-in.
__global__ __launch_bounds__(256, 4) void attn_kernel(const _Float16* __restrict__ qh,
                                                      const _Float16* __restrict__ kh,
                                                      const _Float16* __restrict__ vth,
                                                      _Float16* __restrict__ out) {
    // V dbuf: buf0 SM[0..4095], buf1 SM[4096..8191] (8KB each).
    // Epilogue reuse: EXO 16KB @SM[0], EXS @SM+8192, Os @SM+8320.
    __shared__ _Float16 SM[16384];

    const int t = threadIdx.x;
    const int lane = t & 63, w = t >> 6;          // 4 waves
    const int l15 = lane & 15, quad = lane >> 4;
    const int sw = l15 & 7;                       // V read-side swizzle key
    const int qg = w >> 1, kg = w & 1;
    const int q0 = blockIdx.x * 64;
    const int bh = blockIdx.y;
    const int b = bh >> 4, h = bh & 15;

    const _Float16* Qp = qh + (size_t)bh * 131072 + q0 * 64;
    const _Float16* Kp = kh + (size_t)bh * 131072;
    const _Float16* VTp = vth + (size_t)bh * 131072;

    // K lane base: fragment (Ti,kk) of tile kt at Kl[kt*64 + Ti*1024 + kk*32]
    const _Float16* Kl = Kp + (kg * 32 + l15) * 64 + quad * 8;

    // V staging: 256 chunks of 16B per 32-row half, 1 per thread.
    // dest slot (row = t>>3, cs = t&7) holds global chunk cg = cs ^ (row&7).
    const int row0 = t >> 3, cg0 = (t & 7) ^ (row0 & 7);
    const _Float16* V0 = &VTp[(size_t)row0 * 2048 + cg0 * 8];          // + kt
    const _Float16* V1 = &VTp[(size_t)(32 + row0) * 2048 + cg0 * 8];   // (32+row0)&7 == row0&7

    const floatx4 zf = {0.f, 0.f, 0.f, 0.f};

    half8 qf[2][2];   // [nh][kk], pre-scaled by 0.125
#pragma unroll
    for (int nh = 0; nh < 2; ++nh)
#pragma unroll
        for (int kk = 0; kk < 2; ++kk) {
            half8 q = *(const half8*)&Qp[(qg * 32 + nh * 16 + l15) * 64 + kk * 32 + quad * 8];
#pragma unroll
            for (int j = 0; j < 8; ++j) q[j] = q[j] * (_Float16)0.125f;
            qf[nh][kk] = q;
        }

    // ---------------- pass 1: row max, barrier-free, K global->reg ------------
    float rmax[2] = {-1.0e30f, -1.0e30f};
    {
        half8 ka[2][2], kb[2][2];   // [Ti][kk], 2-deep ping-pong
#pragma unroll
        for (int Ti = 0; Ti < 2; ++Ti)
#pragma unroll
            for (int kk = 0; kk < 2; ++kk)
                ka[Ti][kk] = *(const half8*)&Kl[Ti * 1024 + kk * 32];
        for (int kt = 0; kt < 2048; kt += 128) {
#pragma unroll
            for (int Ti = 0; Ti < 2; ++Ti)
#pragma unroll
                for (int kk = 0; kk < 2; ++kk)
                    kb[Ti][kk] = *(const half8*)&Kl[(size_t)(kt + 64) * 64 + Ti * 1024 + kk * 32];
            floatx4 sa[2][2];
#pragma unroll
            for (int Ti = 0; Ti < 2; ++Ti) { sa[Ti][0] = zf; sa[Ti][1] = zf; }
            __builtin_amdgcn_s_setprio(1);
#pragma unroll
            for (int kk = 0; kk < 2; ++kk)
#pragma unroll
                for (int Ti = 0; Ti < 2; ++Ti)
#pragma unroll
                    for (int nh = 0; nh < 2; ++nh)
                        sa[Ti][nh] = __builtin_amdgcn_mfma_f32_16x16x32_f16(ka[Ti][kk], qf[nh][kk],
                                                                            sa[Ti][nh], 0, 0, 0);
            __builtin_amdgcn_s_setprio(0);
#pragma unroll
            for (int Ti = 0; Ti < 2; ++Ti)
#pragma unroll
                for (int nh = 0; nh < 2; ++nh)
#pragma unroll
                    for (int r = 0; r < 4; ++r)
                        rmax[nh] = fmaxf(rmax[nh], sa[Ti][nh][r]);
            if (kt + 128 < 2048) {
#pragma unroll
                for (int Ti = 0; Ti < 2; ++Ti)
#pragma unroll
                    for (int kk = 0; kk < 2; ++kk)
                        ka[Ti][kk] = *(const half8*)&Kl[(size_t)(kt + 128) * 64 + Ti * 1024 + kk * 32];
            }
            floatx4 sb[2][2];
#pragma unroll
            for (int Ti = 0; Ti < 2; ++Ti) { sb[Ti][0] = zf; sb[Ti][1] = zf; }
            __builtin_amdgcn_s_setprio(1);
#pragma unroll
            for (int kk = 0; kk < 2; ++kk)
#pragma unroll
                for (int Ti = 0; Ti < 2; ++Ti)
#pragma unroll
                    for (int nh = 0; nh < 2; ++nh)
                        sb[Ti][nh] = __builtin_amdgcn_mfma_f32_16x16x32_f16(kb[Ti][kk], qf[nh][kk],
                                                                            sb[Ti][nh], 0, 0, 0);
            __builtin_amdgcn_s_setprio(0);
#pragma unroll
            for (int Ti = 0; Ti < 2; ++Ti)
#pragma unroll
                for (int nh = 0; nh < 2; ++nh)
#pragma unroll
                    for (int r = 0; r < 4; ++r)
                        rmax[nh] = fmaxf(rmax[nh], sb[Ti][nh][r]);
        }
    }
#pragma unroll
    for (int nh = 0; nh < 2; ++nh) {
        rmax[nh] = fmaxf(rmax[nh], __shfl_xor(rmax[nh], 16, 64));
        rmax[nh] = fmaxf(rmax[nh], __shfl_xor(rmax[nh], 32, 64));
    }
    // cross-wave (kg) max combine via LDS floats (pass 1 used no LDS)
    {
        float* EXM = (float*)SM;
        if (quad == 0) {
#pragma unroll
            for (int nh = 0; nh < 2; ++nh)
                EXM[((qg * 2 + nh) * 2 + kg) * 16 + l15] = rmax[nh];
        }
        __syncthreads();
#pragma unroll
        for (int nh = 0; nh < 2; ++nh)
            rmax[nh] = fmaxf(EXM[((qg * 2 + nh) * 2 + 0) * 16 + l15],
                             EXM[((qg * 2 + nh) * 2 + 1) * 16 + l15]);
        __syncthreads();   // EXM reads done before V staging overwrites
    }
    const floatx4 xmv[2] = {{-rmax[0], -rmax[0], -rmax[0], -rmax[0]},
                            {-rmax[1], -rmax[1], -rmax[1], -rmax[1]}};

    // ---------------- pass 2: p = s3(x); Sum p; P·V ---------------------------
    const half2v cA = {(_Float16)(-1.0f / 6.0f), (_Float16)(-1.0f / 6.0f)};
    const half2v cB = {(_Float16)0.5f, (_Float16)0.5f};
    const half2v cC = {(_Float16)-1.0f, (_Float16)-1.0f};
    const half2v cD = {(_Float16)1.0f, (_Float16)1.0f};

    float rsum[2] = {0.f, 0.f};
    floatx4 oacc[4][2];
#pragma unroll
    for (int i = 0; i < 4; ++i) { oacc[i][0] = zf; oacc[i][1] = zf; }

    // prologue: V(0) DMA + K(0) fragment preload
    gl_lds16(V0, &SM[t * 8]);
    gl_lds16(V1, &SM[2048 + t * 8]);
    half8 ka[2][2];
#pragma unroll
    for (int Ti = 0; Ti < 2; ++Ti)
#pragma unroll
        for (int kk = 0; kk < 2; ++kk)
            ka[Ti][kk] = *(const half8*)&Kl[Ti * 1024 + kk * 32];
    __syncthreads();

    for (int kt = 0, cur = 0; kt < 2048; kt += 64, cur ^= 1) {
        if (kt + 64 < 2048) {   // V(t+1) into the buffer freed at last barrier
            _Float16* vd = cur ? &SM[0] : &SM[4096];
            gl_lds16(V0 + (kt + 64), vd + t * 8);
            gl_lds16(V1 + (kt + 64), vd + 2048 + t * 8);
        }
        // sa init = -rmax: the (score - max) shift comes free via the MFMA C-in
        floatx4 sa[2][2];
#pragma unroll
        for (int Ti = 0; Ti < 2; ++Ti) { sa[Ti][0] = xmv[0]; sa[Ti][1] = xmv[1]; }
        __builtin_amdgcn_s_setprio(1);
#pragma unroll
        for (int kk = 0; kk < 2; ++kk)
#pragma unroll
            for (int Ti = 0; Ti < 2; ++Ti)
#pragma unroll
                for (int nh = 0; nh < 2; ++nh)
                    sa[Ti][nh] = __builtin_amdgcn_mfma_f32_16x16x32_f16(ka[Ti][kk], qf[nh][kk],
                                                                        sa[Ti][nh], 0, 0, 0);
        __builtin_amdgcn_s_setprio(0);
        // K(t+1) prefetch — latency hidden under poly+PV below
        if (kt + 64 < 2048) {
#pragma unroll
            for (int Ti = 0; Ti < 2; ++Ti)
#pragma unroll
                for (int kk = 0; kk < 2; ++kk)
                    ka[Ti][kk] = *(const half8*)&Kl[(size_t)(kt + 64) * 64 + Ti * 1024 + kk * 32];
        }
        const _Float16* VTs = cur ? &SM[4096] : &SM[0];
        // PV over this wave's k-half (kg); s3 in packed fp16 straight into pb
        half8 vf[4];
#pragma unroll
        for (int di = 0; di < 4; ++di) {
            const int bl = (di * 16 + l15) << 6;
            const int clo = (((kg << 2) + (quad >> 1)) ^ sw) << 3;
            const int chi = (((kg << 2) + 2 + (quad >> 1)) ^ sw) << 3;
            half4 lo = *(const half4*)&VTs[bl + clo + ((quad & 1) << 2)];
            half4 hi = *(const half4*)&VTs[bl + chi + ((quad & 1) << 2)];
            vf[di] = from_lohi(lo, hi);
        }
#pragma unroll
        for (int nh = 0; nh < 2; ++nh) {
            half2v p2m[4];
#pragma unroll
            for (int m = 0; m < 4; ++m) {
                int Ti = m >> 1;
                int r0 = (m & 1) * 2;
                half2v x2 = cvt_pk(sa[Ti][nh][r0], sa[Ti][nh][r0 + 1]);
                half2v hp = __builtin_elementwise_fma(x2, cA, cB);
                hp = __builtin_elementwise_fma(x2, hp, cC);
                hp = __builtin_elementwise_fma(x2, hp, cD);
                half2v p2 = rcp2(hp);
                rsum[nh] = dot2acc(p2, rsum[nh]);
                p2m[m] = p2;
            }
            half8 pb = from4(p2m[0], p2m[1], p2m[2], p2m[3]);
            __builtin_amdgcn_s_setprio(1);
#pragma unroll
            for (int di = 0; di < 4; ++di)
                oacc[di][nh] = __builtin_amdgcn_mfma_f32_16x16x32_f16(vf[di], pb,
                                                                      oacc[di][nh], 0, 0, 0);
            __builtin_amdgcn_s_setprio(0);
        }
        __syncthreads();   // drains V(t+1) DMA; all waves done reading cur
    }

#pragma unroll
    for (int nh = 0; nh < 2; ++nh) {
        rsum[nh] += __shfl_xor(rsum[nh], 16, 64);
        rsum[nh] += __shfl_xor(rsum[nh], 32, 64);
    }

    // ---- cross-wave (kg) combine: O partials + rsum, once per block ----------
    // EXO: 4096 floats (16KB) at SM[0]; EXS: 64 floats at byte 16384;
    // Os: 64x72 halfs at SM+8320. Loop ended with barrier.
    float* EXO = (float*)SM;
    float* EXS = (float*)(SM + 8192);
    _Float16* Os = SM + 8320;
    if (kg) {
#pragma unroll
        for (int nh = 0; nh < 2; ++nh)
#pragma unroll
            for (int di = 0; di < 4; ++di)
                *(floatx4*)&EXO[(((((qg * 2 + nh) * 4 + di) * 4 + quad) * 16) + l15) * 4] =
                    oacc[di][nh];
        if (quad == 0) {
#pragma unroll
            for (int nh = 0; nh < 2; ++nh)
                EXS[(qg * 2 + nh) * 16 + l15] = rsum[nh];
        }
    }
    __syncthreads();
    if (!kg) {
        float inv[2];
#pragma unroll
        for (int nh = 0; nh < 2; ++nh)
            inv[nh] = 1.0f / (rsum[nh] + EXS[(qg * 2 + nh) * 16 + l15]);
#pragma unroll
        for (int nh = 0; nh < 2; ++nh)
#pragma unroll
            for (int di = 0; di < 4; ++di) {
                floatx4 part = *(const floatx4*)
                    &EXO[(((((qg * 2 + nh) * 4 + di) * 4 + quad) * 16) + l15) * 4];
                half4 hv;
#pragma unroll
                for (int r = 0; r < 4; ++r)
                    hv[r] = (_Float16)((oacc[di][nh][r] + part[r]) * inv[nh]);
                *(half4*)&Os[(qg * 32 + nh * 16 + l15) * 72 + di * 16 + quad * 4] = hv;
            }
    }
    __syncthreads();
    // coalesced global write: 64 rows x 64 cols, 512 chunks of 16B, 2 per thread
    _Float16* Op = out + (size_t)(b * 2048 + q0) * 1024 + h * 64;
#pragma unroll
    for (int it = 0; it < 2; ++it) {
        int cc = it * 256 + t;
        int r = cc >> 3, c8 = cc & 7;
        *(half8*)&Op[(size_t)r * 1024 + c8 * 8] = *(const half8*)&Os[r * 72 + c8 * 8];
    }
}

// ---------------- launch ---------------------------------------------------------
extern "C" void kernel_launch(void* const* d_in, const int* in_sizes, int n_in,
                              void* d_out, int out_size, void* d_ws, size_t ws_size,
                              hipStream_t stream) {
    const float* x_f = (const float*)d_in[0];     // [2,2048,1024] fp32
    const float* wqkv_f = (const float*)d_in[1];  // [3072,1024] fp32
    const float* wout_f = (const float*)d_in[2];  // [1024,1024] fp32
    const float* bias_f = (const float*)d_in[3];  // [1024] fp32

    // workspace: 38 MB, with aliasing (aoh reuses xh; woh reuses wqh).
    // ORDERING CONSTRAINT: woh is written only AFTER gemm_qkv consumes wqh.
    char* ws = (char*)d_ws;
    _Float16* xh = (_Float16*)(ws);                   // [4096][1024] f16, 8 MB
    _Float16* aoh = xh;                               // alias: live after gemm_qkv
    _Float16* wqh = (_Float16*)(ws + 8388608);        // [3072][1024] f16, 6 MB
    _Float16* woh = wqh;                              // alias: live after gemm_qkv
    _Float16* qh = (_Float16*)(ws + 14680064);        // [32][2048][64] f16, 8 MB
    _Float16* kh = (_Float16*)(ws + 23068672);        // [32][2048][64] f16, 8 MB
    _Float16* vth = (_Float16*)(ws + 31457280);       // [32][64][2048] f16, 8 MB

    cvt_xw<<<7168, 256, 0, stream>>>((const floatx4*)x_f, (const floatx4*)wqkv_f,
                                     (half4*)xh, (half4*)wqh);
    gemm_qkv<<<dim3(24, 32), 256, 0, stream>>>(xh, wqh, qh, kh, vth);
    cvt_f32_f16<<<1024, 256, 0, stream>>>((const floatx4*)wout_f, (half4*)woh, 262144);
    attn_kernel<<<dim3(32, 32), 256, 0, stream>>>(qh, kh, vth, aoh);
    gemm_out<<<dim3(8, 64), 256, 0, stream>>>(aoh, woh, (float*)d_out, bias_f);
}

// Round 6
// 207.589 us; speedup vs baseline: 1.2714x; 1.2714x over previous
//
#include <hip/hip_runtime.h>

typedef _Float16 half8 __attribute__((ext_vector_type(8)));
typedef _Float16 half4 __attribute__((ext_vector_type(4)));
typedef _Float16 half2v __attribute__((ext_vector_type(2)));
typedef float floatx4 __attribute__((ext_vector_type(4)));
typedef unsigned int uint2v __attribute__((ext_vector_type(2)));
typedef unsigned int uint4v __attribute__((ext_vector_type(4)));

__device__ __forceinline__ void gl_lds16(const _Float16* g, _Float16* l) {
    __builtin_amdgcn_global_load_lds(
        (const __attribute__((address_space(1))) void*)g,
        (__attribute__((address_space(3))) void*)l, 16, 0, 0);
}

__device__ __forceinline__ half2v cvt_pk(float a, float b) {
    return __builtin_bit_cast(half2v, __builtin_amdgcn_cvt_pkrtz(a, b));
}

__device__ __forceinline__ half2v rcp2(half2v d) {
#if __has_builtin(__builtin_amdgcn_rcph)
    half2v r;
    r[0] = __builtin_amdgcn_rcph(d[0]);
    r[1] = __builtin_amdgcn_rcph(d[1]);
    return r;
#else
    half2v r;
    r[0] = (_Float16)__builtin_amdgcn_rcpf((float)d[0]);
    r[1] = (_Float16)__builtin_amdgcn_rcpf((float)d[1]);
    return r;
#endif
}

__device__ __forceinline__ float dot2acc(half2v a, float acc) {
#if __has_builtin(__builtin_amdgcn_fdot2)
    const half2v one = {(_Float16)1.0f, (_Float16)1.0f};
    return __builtin_amdgcn_fdot2(a, one, acc, false);
#else
    return acc + (float)a[0] + (float)a[1];
#endif
}

// concat 4 packed half2 (each one dword) into a half8 — no element inserts
__device__ __forceinline__ half8 from4(half2v a, half2v b, half2v c, half2v d) {
    uint4v u = {__builtin_bit_cast(unsigned int, a), __builtin_bit_cast(unsigned int, b),
                __builtin_bit_cast(unsigned int, c), __builtin_bit_cast(unsigned int, d)};
    return __builtin_bit_cast(half8, u);
}

// concat two half4 (two dword-pairs) into a half8 — no element inserts
__device__ __forceinline__ half8 from_lohi(half4 lo, half4 hi) {
    uint2v l = __builtin_bit_cast(uint2v, lo);
    uint2v h = __builtin_bit_cast(uint2v, hi);
    uint4v u = {l[0], l[1], h[0], h[1]};
    return __builtin_bit_cast(half8, u);
}

// ---------------- fp32 -> fp16 convert: x and w_qkv fused (runs BEFORE gemm_qkv) -
__global__ __launch_bounds__(256) void cvt_xw(const floatx4* __restrict__ x,
                                              const floatx4* __restrict__ wq,
                                              half4* __restrict__ xh,
                                              half4* __restrict__ wqh) {
    int i = blockIdx.x * 256 + threadIdx.x;   // 0..1835007
    floatx4 v;
    half4 h;
    if (i < 1048576) {
        v = x[i];
#pragma unroll
        for (int j = 0; j < 4; ++j) h[j] = (_Float16)v[j];
        xh[i] = h;
    } else {
        int j4 = i - 1048576;
        v = wq[j4];
#pragma unroll
        for (int j = 0; j < 4; ++j) h[j] = (_Float16)v[j];
        wqh[j4] = h;
    }
}

// wout cvt — MUST run after gemm_qkv (woh aliases wqh)
__global__ __launch_bounds__(256) void cvt_f32_f16(const floatx4* __restrict__ in,
                                                   half4* __restrict__ out, int n4) {
    int i = blockIdx.x * 256 + threadIdx.x;
    if (i >= n4) return;
    floatx4 v = in[i];
    half4 h;
#pragma unroll
    for (int j = 0; j < 4; ++j) h[j] = (_Float16)v[j];
    out[i] = h;
}

// ---------------- GEMM1: qkv = xh @ wqh^T -> head-major q/k/vt (fp16 in/out) -----
// M=4096, N=3072, K=1024. 128x128 tile, BK=32, 256 thr, DMA staging.
// R6: vth is stored KEY-PERMUTED within each 64-key tile:
//   stored position p = c*32 + q*8 + j  holds key  c*32 + (j>>2)*16 + q*4 + (j&3)
// so attn's PV fragment (kg=c, quad=q) is one contiguous 16B ds_read_b128.
__global__ __launch_bounds__(256) void gemm_qkv(const _Float16* __restrict__ A,
                                                const _Float16* __restrict__ B,
                                                _Float16* __restrict__ qh,
                                                _Float16* __restrict__ kh,
                                                _Float16* __restrict__ vth) {
    const int K = 1024;
    __shared__ _Float16 SH[128 * 68];   // As 8KB | Bs 8KB; epilogue 128x68
    _Float16* As = SH;
    _Float16* Bs = SH + 4096;
    const int t = threadIdx.x;
    const int lane = t & 63, w = t >> 6;
    const int l15 = lane & 15, quad = lane >> 4;
    const int wm = w >> 1, wn = w & 1;
    const int m0 = blockIdx.y * 128, n0 = blockIdx.x * 128;

    floatx4 acc[4][4];
    const floatx4 zf = {0.f, 0.f, 0.f, 0.f};
#pragma unroll
    for (int i = 0; i < 4; ++i)
#pragma unroll
        for (int j = 0; j < 4; ++j) acc[i][j] = zf;

    for (int kt = 0; kt < K; kt += 32) {
        __syncthreads();
#pragma unroll
        for (int it = 0; it < 2; ++it) {    // 512 chunks of 16B per matrix
            int cc = it * 256 + t;
            int row = cc >> 2, kc = cc & 3;
            gl_lds16(&A[(size_t)(m0 + row) * K + kt + kc * 8], &As[cc * 8]);
            gl_lds16(&B[(size_t)(n0 + row) * K + kt + kc * 8], &Bs[cc * 8]);
        }
        __syncthreads();
        half8 af[4], bfr[4];
#pragma unroll
        for (int i = 0; i < 4; ++i)
            af[i] = *(const half8*)&As[(wm * 64 + i * 16 + l15) * 32 + quad * 8];
#pragma unroll
        for (int i = 0; i < 4; ++i)
            bfr[i] = *(const half8*)&Bs[(wn * 64 + i * 16 + l15) * 32 + quad * 8];
#pragma unroll
        for (int mi = 0; mi < 4; ++mi)
#pragma unroll
            for (int ni = 0; ni < 4; ++ni)
                acc[mi][ni] = __builtin_amdgcn_mfma_f32_16x16x32_f16(af[mi], bfr[ni],
                                                                     acc[mi][ni], 0, 0, 0);
    }

    // ---- epilogue: two 128x64 col-halves staged through LDS, coalesced writes ----
    const int b = m0 >> 11, s0 = m0 & 2047;
#pragma unroll
    for (int hf = 0; hf < 2; ++hf) {
        __syncthreads();
        if (wn == hf) {
#pragma unroll
            for (int mi = 0; mi < 4; ++mi)
#pragma unroll
                for (int ni = 0; ni < 4; ++ni)
#pragma unroll
                    for (int r = 0; r < 4; ++r)
                        SH[(wm * 64 + mi * 16 + quad * 4 + r) * 68 + ni * 16 + l15] =
                            (_Float16)acc[mi][ni][r];
        }
        __syncthreads();
        const int cbase = n0 + hf * 64;
        if (n0 < 2048) {
            const int hh = (cbase & 1023) >> 6;
            _Float16* dst = (n0 < 1024 ? qh : kh) + (size_t)((b << 4) | hh) * 131072;
#pragma unroll
            for (int it = 0; it < 4; ++it) {
                int cc = it * 256 + t;
                int r = cc >> 3, c8 = cc & 7;
                half4 lo = *(const half4*)&SH[r * 68 + c8 * 8];
                half4 hi = *(const half4*)&SH[r * 68 + c8 * 8 + 4];
                *(half8*)&dst[(size_t)(s0 + r) * 64 + c8 * 8] = from_lohi(lo, hi);
            }
        } else {
            const int hh = (cbase - 2048) >> 6;
            _Float16* dst = vth + (size_t)((b << 4) | hh) * 131072;
#pragma unroll
            for (int it = 0; it < 4; ++it) {
                int cc = it * 256 + t;
                int d = cc >> 4, s8 = cc & 15;
                // key-permuted gather: stored p=(s8&7)*8+j <- key base+(j>>2)*16+(j&3)
                int sq = s8 & 7;
                int base = (s8 >> 3) * 64 + (sq >> 2) * 32 + (sq & 3) * 4;
                half8 v;
#pragma unroll
                for (int j = 0; j < 8; ++j)
                    v[j] = SH[(base + (j >> 2) * 16 + (j & 3)) * 68 + d];
                *(half8*)&dst[(size_t)d * 2048 + s0 + s8 * 8] = v;
            }
        }
    }
}

// ---------------- GEMM2: out = aoh @ woh^T + b_out -> fp32 -----------------------
// M=4096, N=1024, K=1024. 64x128 tile, BK=32, 256 thr, DMA staging.
__global__ __launch_bounds__(256) void gemm_out(const _Float16* __restrict__ A,
                                                const _Float16* __restrict__ B,
                                                float* __restrict__ C,
                                                const float* __restrict__ bias) {
    const int K = 1024, N = 1024;
    __shared__ _Float16 SH[6144];   // As 64x32 (4KB) | Bs 128x32 (8KB)
    _Float16* As = SH;
    _Float16* Bs = SH + 2048;
    const int t = threadIdx.x;
    const int lane = t & 63, w = t >> 6;
    const int l15 = lane & 15, quad = lane >> 4;
    const int wm = w >> 1, wn = w & 1;
    const int m0 = blockIdx.y * 64, n0 = blockIdx.x * 128;

    floatx4 acc[2][4];
    const floatx4 zf = {0.f, 0.f, 0.f, 0.f};
#pragma unroll
    for (int i = 0; i < 2; ++i)
#pragma unroll
        for (int j = 0; j < 4; ++j) acc[i][j] = zf;

    for (int kt = 0; kt < K; kt += 32) {
        __syncthreads();
        {   // A: 256 chunks of 16B
            int row = t >> 2, kc = t & 3;
            gl_lds16(&A[(size_t)(m0 + row) * K + kt + kc * 8], &As[t * 8]);
        }
#pragma unroll
        for (int it = 0; it < 2; ++it) {    // B: 512 chunks of 16B
            int cc = it * 256 + t;
            int row = cc >> 2, kc = cc & 3;
            gl_lds16(&B[(size_t)(n0 + row) * K + kt + kc * 8], &Bs[cc * 8]);
        }
        __syncthreads();
        half8 af[2], bfr[4];
#pragma unroll
        for (int i = 0; i < 2; ++i)
            af[i] = *(const half8*)&As[(wm * 32 + i * 16 + l15) * 32 + quad * 8];
#pragma unroll
        for (int i = 0; i < 4; ++i)
            bfr[i] = *(const half8*)&Bs[(wn * 64 + i * 16 + l15) * 32 + quad * 8];
#pragma unroll
        for (int mi = 0; mi < 2; ++mi)
#pragma unroll
            for (int ni = 0; ni < 4; ++ni)
                acc[mi][ni] = __builtin_amdgcn_mfma_f32_16x16x32_f16(af[mi], bfr[ni],
                                                                     acc[mi][ni], 0, 0, 0);
    }

#pragma unroll
    for (int mi = 0; mi < 2; ++mi) {
#pragma unroll
        for (int ni = 0; ni < 4; ++ni) {
            int col = n0 + wn * 64 + ni * 16 + l15;
            float bv = bias[col];
#pragma unroll
            for (int r = 0; r < 4; ++r) {
                int row = m0 + wm * 32 + mi * 16 + quad * 4 + r;
                C[(size_t)row * N + col] = acc[mi][ni][r] + bv;
            }
        }
    }
}

// ---------------- fused two-pass stablemax attention (split-K, 4 waves) ----------
// R6 = R3 base (best measured: 73.9us; R4/R5's K-from-global refuted, reverted)
// + two fixes:
// (1) V reads are single ds_read_b128 (vth stored key-permuted by gemm_qkv).
//     R2/R3/R5 showed SQ_LDS_BANK_CONFLICT==4292608 invariant incl. a kernel
//     with NO K ds_reads => conflicts were entirely the V b64 gather. Gone now.
// (2) XCD L2 locality: bh = blockIdx.x (fastest) so XCD k owns heads {k,k+8,..}
//     -> 2MB K/V working set per XCD (fits 4MB L2), reused by all 32 q-blocks.
// Split-K: block = 64 q-rows; wave (qg,kg) owns 32q x kg-half(32) of each tile;
// cross-wave combine once per block (rmax / rsum+O) via LDS scratch.
// DMA dbuf staging (K+V), XOR-chunk swizzle, xm baked into pass-2 C-in, setprio.
// Q pre-scaled by 0.125; s3 in packed fp16; P never touches LDS.
__global__ __launch_bounds__(256, 4) void attn_kernel(const _Float16* __restrict__ qh,
                                                      const _Float16* __restrict__ kh,
                                                      const _Float16* __restrict__ vth,
                                                      _Float16* __restrict__ out) {
    // Ks0 | Ks1 | VTs0 | VTs1, each 64x64 f16 = 8KB -> 32KB; reused as exchange+O
    __shared__ _Float16 SM[16384];

    const int t = threadIdx.x;
    const int lane = t & 63, w = t >> 6;          // 4 waves
    const int l15 = lane & 15, quad = lane >> 4;
    const int sw = l15 & 7;                       // read-side swizzle key (row&7)
    const int qg = w >> 1, kg = w & 1;
    const int bh = blockIdx.x;                    // fastest dim -> XCD head groups
    const int q0 = blockIdx.y * 64;
    const int b = bh >> 4, h = bh & 15;

    const _Float16* Qp = qh + (size_t)bh * 131072 + q0 * 64;
    const _Float16* Kp = kh + (size_t)bh * 131072;
    const _Float16* VTp = vth + (size_t)bh * 131072;

    // staging: 512 chunks of 16B per tile, 2 per thread.
    // dest slot (row = cc>>3, cs = cc&7) holds global chunk cg = cs ^ (row&7).
    const int row0 = t >> 3, cg0 = (t & 7) ^ (row0 & 7);
    const _Float16* K0 = &Kp[(size_t)row0 * 64 + cg0 * 8];             // + kt*64
    const _Float16* K1 = &Kp[(size_t)(32 + row0) * 64 + cg0 * 8];      // row&7 same
    const _Float16* V0 = &VTp[(size_t)row0 * 2048 + cg0 * 8];          // + kt
    const _Float16* V1 = &VTp[(size_t)(32 + row0) * 2048 + cg0 * 8];

    const floatx4 zf = {0.f, 0.f, 0.f, 0.f};

    half8 qf[2][2];   // [nh][kk], pre-scaled by 0.125
#pragma unroll
    for (int nh = 0; nh < 2; ++nh)
#pragma unroll
        for (int kk = 0; kk < 2; ++kk) {
            half8 q = *(const half8*)&Qp[(qg * 32 + nh * 16 + l15) * 64 + kk * 32 + quad * 8];
#pragma unroll
            for (int j = 0; j < 8; ++j) q[j] = q[j] * (_Float16)0.125f;
            qf[nh][kk] = q;
        }

    // ---------------- pass 1: row max over (scaled) scores --------------------
    float rmax[2] = {-1.0e30f, -1.0e30f};
    gl_lds16(K0, &SM[t * 8]);
    gl_lds16(K1, &SM[2048 + t * 8]);
    __syncthreads();
    for (int kt = 0, cur = 0; kt < 2048; kt += 64, cur ^= 1) {
        if (kt + 64 < 2048) {
            _Float16* kd = cur ? &SM[0] : &SM[4096];
            gl_lds16(K0 + (size_t)(kt + 64) * 64, kd + t * 8);
            gl_lds16(K1 + (size_t)(kt + 64) * 64, kd + 2048 + t * 8);
        }
        const _Float16* Ks = cur ? &SM[4096] : &SM[0];
        floatx4 sa[2][2];
#pragma unroll
        for (int Ti = 0; Ti < 2; ++Ti) { sa[Ti][0] = zf; sa[Ti][1] = zf; }
#pragma unroll
        for (int kk = 0; kk < 2; ++kk) {
            half8 kf[2];
#pragma unroll
            for (int Ti = 0; Ti < 2; ++Ti)
                kf[Ti] = *(const half8*)&Ks[(((kg * 2 + Ti) * 16 + l15) << 6) +
                                            ((((kk << 2) + quad) ^ sw) << 3)];
            __builtin_amdgcn_s_setprio(1);
#pragma unroll
            for (int Ti = 0; Ti < 2; ++Ti)
#pragma unroll
                for (int nh = 0; nh < 2; ++nh)
                    sa[Ti][nh] = __builtin_amdgcn_mfma_f32_16x16x32_f16(kf[Ti], qf[nh][kk],
                                                                        sa[Ti][nh], 0, 0, 0);
            __builtin_amdgcn_s_setprio(0);
        }
#pragma unroll
        for (int Ti = 0; Ti < 2; ++Ti)
#pragma unroll
            for (int nh = 0; nh < 2; ++nh)
#pragma unroll
                for (int r = 0; r < 4; ++r)
                    rmax[nh] = fmaxf(rmax[nh], sa[Ti][nh][r]);
        __syncthreads();
    }
#pragma unroll
    for (int nh = 0; nh < 2; ++nh) {
        rmax[nh] = fmaxf(rmax[nh], __shfl_xor(rmax[nh], 16, 64));
        rmax[nh] = fmaxf(rmax[nh], __shfl_xor(rmax[nh], 32, 64));
    }
    // cross-wave (kg) max combine via LDS floats (loop ended with barrier)
    {
        float* EXM = (float*)SM;
        if (quad == 0) {
#pragma unroll
            for (int nh = 0; nh < 2; ++nh)
                EXM[((qg * 2 + nh) * 2 + kg) * 16 + l15] = rmax[nh];
        }
        __syncthreads();
#pragma unroll
        for (int nh = 0; nh < 2; ++nh)
            rmax[nh] = fmaxf(EXM[((qg * 2 + nh) * 2 + 0) * 16 + l15],
                             EXM[((qg * 2 + nh) * 2 + 1) * 16 + l15]);
        __syncthreads();   // EX reads done before pass-2 DMA overwrites
    }
    const floatx4 xmv[2] = {{-rmax[0], -rmax[0], -rmax[0], -rmax[0]},
                            {-rmax[1], -rmax[1], -rmax[1], -rmax[1]}};

    // ---------------- pass 2: p = s3(x); Sum p; P·V ---------------------------
    const half2v cA = {(_Float16)(-1.0f / 6.0f), (_Float16)(-1.0f / 6.0f)};
    const half2v cB = {(_Float16)0.5f, (_Float16)0.5f};
    const half2v cC = {(_Float16)-1.0f, (_Float16)-1.0f};
    const half2v cD = {(_Float16)1.0f, (_Float16)1.0f};

    float rsum[2] = {0.f, 0.f};
    floatx4 oacc[4][2];
#pragma unroll
    for (int i = 0; i < 4; ++i) { oacc[i][0] = zf; oacc[i][1] = zf; }

    gl_lds16(K0, &SM[t * 8]);
    gl_lds16(K1, &SM[2048 + t * 8]);
    gl_lds16(V0, &SM[8192 + t * 8]);
    gl_lds16(V1, &SM[8192 + 2048 + t * 8]);
    __syncthreads();
    for (int kt = 0, cur = 0; kt < 2048; kt += 64, cur ^= 1) {
        if (kt + 64 < 2048) {
            _Float16* kd = cur ? &SM[0] : &SM[4096];
            _Float16* vd = cur ? &SM[8192] : &SM[12288];
            gl_lds16(K0 + (size_t)(kt + 64) * 64, kd + t * 8);
            gl_lds16(K1 + (size_t)(kt + 64) * 64, kd + 2048 + t * 8);
            gl_lds16(V0 + (kt + 64), vd + t * 8);
            gl_lds16(V1 + (kt + 64), vd + 2048 + t * 8);
        }
        const _Float16* Ks = cur ? &SM[4096] : &SM[0];
        const _Float16* VTs = cur ? &SM[12288] : &SM[8192];

        // sa init = -rmax: the (score - max) shift comes free via the MFMA C-in
        floatx4 sa[2][2];
#pragma unroll
        for (int Ti = 0; Ti < 2; ++Ti) { sa[Ti][0] = xmv[0]; sa[Ti][1] = xmv[1]; }
#pragma unroll
        for (int kk = 0; kk < 2; ++kk) {
            half8 kf[2];
#pragma unroll
            for (int Ti = 0; Ti < 2; ++Ti)
                kf[Ti] = *(const half8*)&Ks[(((kg * 2 + Ti) * 16 + l15) << 6) +
                                            ((((kk << 2) + quad) ^ sw) << 3)];
            __builtin_amdgcn_s_setprio(1);
#pragma unroll
            for (int Ti = 0; Ti < 2; ++Ti)
#pragma unroll
                for (int nh = 0; nh < 2; ++nh)
                    sa[Ti][nh] = __builtin_amdgcn_mfma_f32_16x16x32_f16(kf[Ti], qf[nh][kk],
                                                                        sa[Ti][nh], 0, 0, 0);
            __builtin_amdgcn_s_setprio(0);
        }
        // PV over this wave's k-half (kg): V fragment is ONE b128 (pre-permuted
        // vth), slot chunk = fragment chunk ^ sw. s3 in packed fp16 into pb.
        half8 vf[4];
#pragma unroll
        for (int di = 0; di < 4; ++di)
            vf[di] = *(const half8*)&VTs[((di * 16 + l15) << 6) +
                                         ((((kg << 2) + quad) ^ sw) << 3)];
#pragma unroll
        for (int nh = 0; nh < 2; ++nh) {
            half2v p2m[4];
#pragma unroll
            for (int m = 0; m < 4; ++m) {
                int Ti = m >> 1;
                int r0 = (m & 1) * 2;
                half2v x2 = cvt_pk(sa[Ti][nh][r0], sa[Ti][nh][r0 + 1]);
                half2v hp = __builtin_elementwise_fma(x2, cA, cB);
                hp = __builtin_elementwise_fma(x2, hp, cC);
                hp = __builtin_elementwise_fma(x2, hp, cD);
                half2v p2 = rcp2(hp);
                rsum[nh] = dot2acc(p2, rsum[nh]);
                p2m[m] = p2;
            }
            half8 pb = from4(p2m[0], p2m[1], p2m[2], p2m[3]);
            __builtin_amdgcn_s_setprio(1);
#pragma unroll
            for (int di = 0; di < 4; ++di)
                oacc[di][nh] = __builtin_amdgcn_mfma_f32_16x16x32_f16(vf[di], pb,
                                                                      oacc[di][nh], 0, 0, 0);
            __builtin_amdgcn_s_setprio(0);
        }
        __syncthreads();
    }

#pragma unroll
    for (int nh = 0; nh < 2; ++nh) {
        rsum[nh] += __shfl_xor(rsum[nh], 16, 64);
        rsum[nh] += __shfl_xor(rsum[nh], 32, 64);
    }

    // ---- cross-wave (kg) combine: O partials + rsum, once per block ----------
    // EXO: 4096 floats (16KB) at SM[0]; EXS: 64 floats at byte 16384;
    // Os: 64x72 halfs at SM+8320. Loop ended with barrier.
    float* EXO = (float*)SM;
    float* EXS = (float*)(SM + 8192);
    _Float16* Os = SM + 8320;
    if (kg) {
#pragma unroll
        for (int nh = 0; nh < 2; ++nh)
#pragma unroll
            for (int di = 0; di < 4; ++di)
                *(floatx4*)&EXO[(((((qg * 2 + nh) * 4 + di) * 4 + quad) * 16) + l15) * 4] =
                    oacc[di][nh];
        if (quad == 0) {
#pragma unroll
            for (int nh = 0; nh < 2; ++nh)
                EXS[(qg * 2 + nh) * 16 + l15] = rsum[nh];
        }
    }
    __syncthreads();
    if (!kg) {
        float inv[2];
#pragma unroll
        for (int nh = 0; nh < 2; ++nh)
            inv[nh] = 1.0f / (rsum[nh] + EXS[(qg * 2 + nh) * 16 + l15]);
#pragma unroll
        for (int nh = 0; nh < 2; ++nh)
#pragma unroll
            for (int di = 0; di < 4; ++di) {
                floatx4 part = *(const floatx4*)
                    &EXO[(((((qg * 2 + nh) * 4 + di) * 4 + quad) * 16) + l15) * 4];
                half4 hv;
#pragma unroll
                for (int r = 0; r < 4; ++r)
                    hv[r] = (_Float16)((oacc[di][nh][r] + part[r]) * inv[nh]);
                *(half4*)&Os[(qg * 32 + nh * 16 + l15) * 72 + di * 16 + quad * 4] = hv;
            }
    }
    __syncthreads();
    // coalesced global write: 64 rows x 64 cols, 512 chunks of 16B, 2 per thread
    _Float16* Op = out + (size_t)(b * 2048 + q0) * 1024 + h * 64;
#pragma unroll
    for (int it = 0; it < 2; ++it) {
        int cc = it * 256 + t;
        int r = cc >> 3, c8 = cc & 7;
        *(half8*)&Op[(size_t)r * 1024 + c8 * 8] = *(const half8*)&Os[r * 72 + c8 * 8];
    }
}

// ---------------- launch ---------------------------------------------------------
extern "C" void kernel_launch(void* const* d_in, const int* in_sizes, int n_in,
                              void* d_out, int out_size, void* d_ws, size_t ws_size,
                              hipStream_t stream) {
    const float* x_f = (const float*)d_in[0];     // [2,2048,1024] fp32
    const float* wqkv_f = (const float*)d_in[1];  // [3072,1024] fp32
    const float* wout_f = (const float*)d_in[2];  // [1024,1024] fp32
    const float* bias_f = (const float*)d_in[3];  // [1024] fp32

    // workspace: 38 MB, with aliasing (aoh reuses xh; woh reuses wqh).
    // ORDERING CONSTRAINT: woh is written only AFTER gemm_qkv consumes wqh.
    char* ws = (char*)d_ws;
    _Float16* xh = (_Float16*)(ws);                   // [4096][1024] f16, 8 MB
    _Float16* aoh = xh;                               // alias: live after gemm_qkv
    _Float16* wqh = (_Float16*)(ws + 8388608);        // [3072][1024] f16, 6 MB
    _Float16* woh = wqh;                              // alias: live after gemm_qkv
    _Float16* qh = (_Float16*)(ws + 14680064);        // [32][2048][64] f16, 8 MB
    _Float16* kh = (_Float16*)(ws + 23068672);        // [32][2048][64] f16, 8 MB
    _Float16* vth = (_Float16*)(ws + 31457280);       // [32][64][2048] f16, 8 MB (key-permuted)

    cvt_xw<<<7168, 256, 0, stream>>>((const floatx4*)x_f, (const floatx4*)wqkv_f,
                                     (half4*)xh, (half4*)wqh);
    gemm_qkv<<<dim3(24, 32), 256, 0, stream>>>(xh, wqh, qh, kh, vth);
    cvt_f32_f16<<<1024, 256, 0, stream>>>((const floatx4*)wout_f, (half4*)woh, 262144);
    attn_kernel<<<dim3(32, 32), 256, 0, stream>>>(qh, kh, vth, aoh);
    gemm_out<<<dim3(8, 64), 256, 0, stream>>>(aoh, woh, (float*)d_out, bias_f);
}

// Round 8
// 204.074 us; speedup vs baseline: 1.2933x; 1.0172x over previous
//
#include <hip/hip_runtime.h>

typedef _Float16 half8 __attribute__((ext_vector_type(8)));
typedef _Float16 half4 __attribute__((ext_vector_type(4)));
typedef _Float16 half2v __attribute__((ext_vector_type(2)));
typedef float floatx4 __attribute__((ext_vector_type(4)));
typedef unsigned int uint2v __attribute__((ext_vector_type(2)));
typedef unsigned int uint4v __attribute__((ext_vector_type(4)));

__device__ __forceinline__ void gl_lds16(const _Float16* g, _Float16* l) {
    __builtin_amdgcn_global_load_lds(
        (const __attribute__((address_space(1))) void*)g,
        (__attribute__((address_space(3))) void*)l, 16, 0, 0);
}

__device__ __forceinline__ half2v cvt_pk(float a, float b) {
    return __builtin_bit_cast(half2v, __builtin_amdgcn_cvt_pkrtz(a, b));
}

__device__ __forceinline__ half2v rcp2(half2v d) {
#if __has_builtin(__builtin_amdgcn_rcph)
    half2v r;
    r[0] = __builtin_amdgcn_rcph(d[0]);
    r[1] = __builtin_amdgcn_rcph(d[1]);
    return r;
#else
    half2v r;
    r[0] = (_Float16)__builtin_amdgcn_rcpf((float)d[0]);
    r[1] = (_Float16)__builtin_amdgcn_rcpf((float)d[1]);
    return r;
#endif
}

__device__ __forceinline__ float dot2acc(half2v a, float acc) {
#if __has_builtin(__builtin_amdgcn_fdot2)
    const half2v one = {(_Float16)1.0f, (_Float16)1.0f};
    return __builtin_amdgcn_fdot2(a, one, acc, false);
#else
    return acc + (float)a[0] + (float)a[1];
#endif
}

// concat 4 packed half2 (each one dword) into a half8 — no element inserts
__device__ __forceinline__ half8 from4(half2v a, half2v b, half2v c, half2v d) {
    uint4v u = {__builtin_bit_cast(unsigned int, a), __builtin_bit_cast(unsigned int, b),
                __builtin_bit_cast(unsigned int, c), __builtin_bit_cast(unsigned int, d)};
    return __builtin_bit_cast(half8, u);
}

// concat two half4 (two dword-pairs) into a half8 — no element inserts
__device__ __forceinline__ half8 from_lohi(half4 lo, half4 hi) {
    uint2v l = __builtin_bit_cast(uint2v, lo);
    uint2v h = __builtin_bit_cast(uint2v, hi);
    uint4v u = {l[0], l[1], h[0], h[1]};
    return __builtin_bit_cast(half8, u);
}

// ---------------- fp32 -> fp16 convert: x and w_qkv fused (runs BEFORE gemm_qkv) -
__global__ __launch_bounds__(256) void cvt_xw(const floatx4* __restrict__ x,
                                              const floatx4* __restrict__ wq,
                                              half4* __restrict__ xh,
                                              half4* __restrict__ wqh) {
    int i = blockIdx.x * 256 + threadIdx.x;   // 0..1835007
    floatx4 v;
    half4 h;
    if (i < 1048576) {
        v = x[i];
#pragma unroll
        for (int j = 0; j < 4; ++j) h[j] = (_Float16)v[j];
        xh[i] = h;
    } else {
        int j4 = i - 1048576;
        v = wq[j4];
#pragma unroll
        for (int j = 0; j < 4; ++j) h[j] = (_Float16)v[j];
        wqh[j4] = h;
    }
}

// wout cvt — MUST run after gemm_qkv (woh aliases wqh)
__global__ __launch_bounds__(256) void cvt_f32_f16(const floatx4* __restrict__ in,
                                                   half4* __restrict__ out, int n4) {
    int i = blockIdx.x * 256 + threadIdx.x;
    if (i >= n4) return;
    floatx4 v = in[i];
    half4 h;
#pragma unroll
    for (int j = 0; j < 4; ++j) h[j] = (_Float16)v[j];
    out[i] = h;
}

// ---------------- GEMM1: qkv = xh @ wqh^T -> head-major q/k/vt (fp16 in/out) -----
// M=4096, N=3072, K=1024. 128x128 tile, BK=32, 256 thr, DMA staging.
// vth is stored KEY-PERMUTED within each 64-key tile:
//   stored position p = c*32 + q*8 + j  holds key  c*32 + (j>>2)*16 + q*4 + (j&3)
// so attn's PV fragment (kg=c, quad=q) is one contiguous 16B ds_read_b128.
__global__ __launch_bounds__(256) void gemm_qkv(const _Float16* __restrict__ A,
                                                const _Float16* __restrict__ B,
                                                _Float16* __restrict__ qh,
                                                _Float16* __restrict__ kh,
                                                _Float16* __restrict__ vth) {
    const int K = 1024;
    __shared__ _Float16 SH[128 * 68];   // As 8KB | Bs 8KB; epilogue 128x68
    _Float16* As = SH;
    _Float16* Bs = SH + 4096;
    const int t = threadIdx.x;
    const int lane = t & 63, w = t >> 6;
    const int l15 = lane & 15, quad = lane >> 4;
    const int wm = w >> 1, wn = w & 1;
    const int m0 = blockIdx.y * 128, n0 = blockIdx.x * 128;

    floatx4 acc[4][4];
    const floatx4 zf = {0.f, 0.f, 0.f, 0.f};
#pragma unroll
    for (int i = 0; i < 4; ++i)
#pragma unroll
        for (int j = 0; j < 4; ++j) acc[i][j] = zf;

    for (int kt = 0; kt < K; kt += 32) {
        __syncthreads();
#pragma unroll
        for (int it = 0; it < 2; ++it) {    // 512 chunks of 16B per matrix
            int cc = it * 256 + t;
            int row = cc >> 2, kc = cc & 3;
            gl_lds16(&A[(size_t)(m0 + row) * K + kt + kc * 8], &As[cc * 8]);
            gl_lds16(&B[(size_t)(n0 + row) * K + kt + kc * 8], &Bs[cc * 8]);
        }
        __syncthreads();
        half8 af[4], bfr[4];
#pragma unroll
        for (int i = 0; i < 4; ++i)
            af[i] = *(const half8*)&As[(wm * 64 + i * 16 + l15) * 32 + quad * 8];
#pragma unroll
        for (int i = 0; i < 4; ++i)
            bfr[i] = *(const half8*)&Bs[(wn * 64 + i * 16 + l15) * 32 + quad * 8];
#pragma unroll
        for (int mi = 0; mi < 4; ++mi)
#pragma unroll
            for (int ni = 0; ni < 4; ++ni)
                acc[mi][ni] = __builtin_amdgcn_mfma_f32_16x16x32_f16(af[mi], bfr[ni],
                                                                     acc[mi][ni], 0, 0, 0);
    }

    // ---- epilogue: two 128x64 col-halves staged through LDS, coalesced writes ----
    const int b = m0 >> 11, s0 = m0 & 2047;
#pragma unroll
    for (int hf = 0; hf < 2; ++hf) {
        __syncthreads();
        if (wn == hf) {
#pragma unroll
            for (int mi = 0; mi < 4; ++mi)
#pragma unroll
                for (int ni = 0; ni < 4; ++ni)
#pragma unroll
                    for (int r = 0; r < 4; ++r)
                        SH[(wm * 64 + mi * 16 + quad * 4 + r) * 68 + ni * 16 + l15] =
                            (_Float16)acc[mi][ni][r];
        }
        __syncthreads();
        const int cbase = n0 + hf * 64;
        if (n0 < 2048) {
            const int hh = (cbase & 1023) >> 6;
            _Float16* dst = (n0 < 1024 ? qh : kh) + (size_t)((b << 4) | hh) * 131072;
#pragma unroll
            for (int it = 0; it < 4; ++it) {
                int cc = it * 256 + t;
                int r = cc >> 3, c8 = cc & 7;
                half4 lo = *(const half4*)&SH[r * 68 + c8 * 8];
                half4 hi = *(const half4*)&SH[r * 68 + c8 * 8 + 4];
                *(half8*)&dst[(size_t)(s0 + r) * 64 + c8 * 8] = from_lohi(lo, hi);
            }
        } else {
            const int hh = (cbase - 2048) >> 6;
            _Float16* dst = vth + (size_t)((b << 4) | hh) * 131072;
#pragma unroll
            for (int it = 0; it < 4; ++it) {
                int cc = it * 256 + t;
                int d = cc >> 4, s8 = cc & 15;
                // key-permuted gather: stored p=(s8&7)*8+j <- key base+(j>>2)*16+(j&3)
                int sq = s8 & 7;
                int base = (s8 >> 3) * 64 + (sq >> 2) * 32 + (sq & 3) * 4;
                half8 v;
#pragma unroll
                for (int j = 0; j < 8; ++j)
                    v[j] = SH[(base + (j >> 2) * 16 + (j & 3)) * 68 + d];
                *(half8*)&dst[(size_t)d * 2048 + s0 + s8 * 8] = v;
            }
        }
    }
}

// ---------------- GEMM2: out = aoh @ woh^T + b_out -> fp32 -----------------------
// M=4096, N=1024, K=1024. 64x128 tile, BK=32, 256 thr, DMA staging.
__global__ __launch_bounds__(256) void gemm_out(const _Float16* __restrict__ A,
                                                const _Float16* __restrict__ B,
                                                float* __restrict__ C,
                                                const float* __restrict__ bias) {
    const int K = 1024, N = 1024;
    __shared__ _Float16 SH[6144];   // As 64x32 (4KB) | Bs 128x32 (8KB)
    _Float16* As = SH;
    _Float16* Bs = SH + 2048;
    const int t = threadIdx.x;
    const int lane = t & 63, w = t >> 6;
    const int l15 = lane & 15, quad = lane >> 4;
    const int wm = w >> 1, wn = w & 1;
    const int m0 = blockIdx.y * 64, n0 = blockIdx.x * 128;

    floatx4 acc[2][4];
    const floatx4 zf = {0.f, 0.f, 0.f, 0.f};
#pragma unroll
    for (int i = 0; i < 2; ++i)
#pragma unroll
        for (int j = 0; j < 4; ++j) acc[i][j] = zf;

    for (int kt = 0; kt < K; kt += 32) {
        __syncthreads();
        {   // A: 256 chunks of 16B
            int row = t >> 2, kc = t & 3;
            gl_lds16(&A[(size_t)(m0 + row) * K + kt + kc * 8], &As[t * 8]);
        }
#pragma unroll
        for (int it = 0; it < 2; ++it) {    // B: 512 chunks of 16B
            int cc = it * 256 + t;
            int row = cc >> 2, kc = cc & 3;
            gl_lds16(&B[(size_t)(n0 + row) * K + kt + kc * 8], &Bs[cc * 8]);
        }
        __syncthreads();
        half8 af[2], bfr[4];
#pragma unroll
        for (int i = 0; i < 2; ++i)
            af[i] = *(const half8*)&As[(wm * 32 + i * 16 + l15) * 32 + quad * 8];
#pragma unroll
        for (int i = 0; i < 4; ++i)
            bfr[i] = *(const half8*)&Bs[(wn * 64 + i * 16 + l15) * 32 + quad * 8];
#pragma unroll
        for (int mi = 0; mi < 2; ++mi)
#pragma unroll
            for (int ni = 0; ni < 4; ++ni)
                acc[mi][ni] = __builtin_amdgcn_mfma_f32_16x16x32_f16(af[mi], bfr[ni],
                                                                     acc[mi][ni], 0, 0, 0);
    }

#pragma unroll
    for (int mi = 0; mi < 2; ++mi) {
#pragma unroll
        for (int ni = 0; ni < 4; ++ni) {
            int col = n0 + wn * 64 + ni * 16 + l15;
            float bv = bias[col];
#pragma unroll
            for (int r = 0; r < 4; ++r) {
                int row = m0 + wm * 32 + mi * 16 + quad * 4 + r;
                C[(size_t)row * N + col] = acc[mi][ni][r] + bv;
            }
        }
    }
}

// ---------------- fused two-pass stablemax attention (split-K, 4 waves) ----------
// R7 RESUBMIT (round-7 bench was GPUAcquisitionTimeout — kernel never ran).
// R7 = R6 structure (best: 69.9us; conflicts 98K, FETCH 12MB — both fixed) with a
// per-wave VALU/overhead efficiency pass. Counter model: MFMA floor 35%, VALU 47%
// (top pipe), TLP capped at 4 blocks/CU by grid geometry. Changes, no sync/math
// restructure:
//  (1) pass-1 tile 64 -> 128 keys (K dbuf 2x16KB = 32KB exactly; pass 1 stages
//      no V) — halves pass-1 barriers + loop overhead.
//  (2) pass-2 manual 2-step unroll: compile-time buffer pointers, no cur-select.
//  (3) pointer-stepping for all DMA sources (no per-step size_t multiplies).
//  (4) xmv/zf fed directly as first-MFMA C-in (C is read-only input) — kills the
//      16 accumulator-init movs per step.
// Unchanged: split-K wave layout (qg,kg), XOR-chunk swizzle, key-permuted vth
// (single b128 V reads), XCD head-grouped grid, cross-wave combine, setprio.
__global__ __launch_bounds__(256, 4) void attn_kernel(const _Float16* __restrict__ qh,
                                                      const _Float16* __restrict__ kh,
                                                      const _Float16* __restrict__ vth,
                                                      _Float16* __restrict__ out) {
    // pass 1: K128 dbuf = SM[0..8191] | SM[8192..16383]
    // pass 2: K buf0 SM[0] K buf1 SM[4096] | V buf0 SM[8192] V buf1 SM[12288]
    // epilogue reuse: EXO 16KB @SM[0], EXS @byte16384, Os @SM+8320
    __shared__ _Float16 SM[16384];

    const int t = threadIdx.x;
    const int lane = t & 63, w = t >> 6;          // 4 waves
    const int l15 = lane & 15, quad = lane >> 4;
    const int sw = l15 & 7;                       // read-side swizzle key (row&7)
    const int qg = w >> 1, kg = w & 1;
    const int bh = blockIdx.x;                    // fastest dim -> XCD head groups
    const int q0 = blockIdx.y * 64;
    const int b = bh >> 4, h = bh & 15;

    const _Float16* Qp = qh + (size_t)bh * 131072 + q0 * 64;
    const _Float16* Kp = kh + (size_t)bh * 131072;
    const _Float16* VTp = vth + (size_t)bh * 131072;

    // staging lane bases: dest slot (row, cs=t&7) holds global chunk cg=cs^(row&7)
    const int row0 = t >> 3, cg0 = (t & 7) ^ (row0 & 7);
    const _Float16* K0 = &Kp[(size_t)row0 * 64 + cg0 * 8];     // +2048/32rows, +4096/tile64
    const _Float16* V0 = &VTp[(size_t)row0 * 2048 + cg0 * 8];  // +65536/32rows, +64/tile64

    const floatx4 zf = {0.f, 0.f, 0.f, 0.f};

    half8 qf[2][2];   // [nh][kk], pre-scaled by 0.125
#pragma unroll
    for (int nh = 0; nh < 2; ++nh)
#pragma unroll
        for (int kk = 0; kk < 2; ++kk) {
            half8 q = *(const half8*)&Qp[(qg * 32 + nh * 16 + l15) * 64 + kk * 32 + quad * 8];
#pragma unroll
            for (int j = 0; j < 8; ++j) q[j] = q[j] * (_Float16)0.125f;
            qf[nh][kk] = q;
        }

    // ---------------- pass 1: row max, 128-key tiles, 16 steps -----------------
    float rmax[2] = {-1.0e30f, -1.0e30f};
#pragma unroll
    for (int s = 0; s < 4; ++s)
        gl_lds16(K0 + s * 2048, &SM[s * 2048 + t * 8]);
    __syncthreads();
    {
        const _Float16* sKp = K0 + 8192;   // tile 1
        for (int i = 0, cur = 0; i < 16; ++i, cur ^= 1) {
            if (i < 15) {
                _Float16* kd = cur ? &SM[0] : &SM[8192];
#pragma unroll
                for (int s = 0; s < 4; ++s)
                    gl_lds16(sKp + s * 2048, kd + s * 2048 + t * 8);
                sKp += 8192;
            }
            const _Float16* Ks = cur ? &SM[8192] : &SM[0];
            half8 kf0[4], kf1[4];
#pragma unroll
            for (int Ti = 0; Ti < 4; ++Ti) {
                const int rb = ((kg * 4 + Ti) * 16 + l15) << 6;
                kf0[Ti] = *(const half8*)&Ks[rb + ((quad ^ sw) << 3)];
                kf1[Ti] = *(const half8*)&Ks[rb + (((4 + quad) ^ sw) << 3)];
            }
            floatx4 sa[4][2];
            __builtin_amdgcn_s_setprio(1);
#pragma unroll
            for (int Ti = 0; Ti < 4; ++Ti)
#pragma unroll
                for (int nh = 0; nh < 2; ++nh)
                    sa[Ti][nh] = __builtin_amdgcn_mfma_f32_16x16x32_f16(kf0[Ti], qf[nh][0],
                                                                        zf, 0, 0, 0);
#pragma unroll
            for (int Ti = 0; Ti < 4; ++Ti)
#pragma unroll
                for (int nh = 0; nh < 2; ++nh)
                    sa[Ti][nh] = __builtin_amdgcn_mfma_f32_16x16x32_f16(kf1[Ti], qf[nh][1],
                                                                        sa[Ti][nh], 0, 0, 0);
            __builtin_amdgcn_s_setprio(0);
#pragma unroll
            for (int Ti = 0; Ti < 4; ++Ti)
#pragma unroll
                for (int nh = 0; nh < 2; ++nh)
#pragma unroll
                    for (int r = 0; r < 4; ++r)
                        rmax[nh] = fmaxf(rmax[nh], sa[Ti][nh][r]);
            __syncthreads();
        }
    }
#pragma unroll
    for (int nh = 0; nh < 2; ++nh) {
        rmax[nh] = fmaxf(rmax[nh], __shfl_xor(rmax[nh], 16, 64));
        rmax[nh] = fmaxf(rmax[nh], __shfl_xor(rmax[nh], 32, 64));
    }
    // cross-wave (kg) max combine via LDS floats (loop ended with barrier)
    {
        float* EXM = (float*)SM;
        if (quad == 0) {
#pragma unroll
            for (int nh = 0; nh < 2; ++nh)
                EXM[((qg * 2 + nh) * 2 + kg) * 16 + l15] = rmax[nh];
        }
        __syncthreads();
#pragma unroll
        for (int nh = 0; nh < 2; ++nh)
            rmax[nh] = fmaxf(EXM[((qg * 2 + nh) * 2 + 0) * 16 + l15],
                             EXM[((qg * 2 + nh) * 2 + 1) * 16 + l15]);
        __syncthreads();   // EX reads done before pass-2 DMA overwrites
    }
    const floatx4 xmv[2] = {{-rmax[0], -rmax[0], -rmax[0], -rmax[0]},
                            {-rmax[1], -rmax[1], -rmax[1], -rmax[1]}};

    // ---------------- pass 2: p = s3(x); Sum p; P·V ---------------------------
    const half2v cA = {(_Float16)(-1.0f / 6.0f), (_Float16)(-1.0f / 6.0f)};
    const half2v cB = {(_Float16)0.5f, (_Float16)0.5f};
    const half2v cC = {(_Float16)-1.0f, (_Float16)-1.0f};
    const half2v cD = {(_Float16)1.0f, (_Float16)1.0f};

    float rsum[2] = {0.f, 0.f};
    floatx4 oacc[4][2];
#pragma unroll
    for (int i = 0; i < 4; ++i) { oacc[i][0] = zf; oacc[i][1] = zf; }

    // one 64-key tile: QK^T (sa from xmv C-in) -> s3 poly -> PV
    auto tile_step = [&](const _Float16* Ks, const _Float16* VTs) {
        half8 kf0[2], kf1[2];
#pragma unroll
        for (int Ti = 0; Ti < 2; ++Ti) {
            const int rb = ((kg * 2 + Ti) * 16 + l15) << 6;
            kf0[Ti] = *(const half8*)&Ks[rb + ((quad ^ sw) << 3)];
            kf1[Ti] = *(const half8*)&Ks[rb + (((4 + quad) ^ sw) << 3)];
        }
        floatx4 sa[2][2];
        __builtin_amdgcn_s_setprio(1);
#pragma unroll
        for (int Ti = 0; Ti < 2; ++Ti)
#pragma unroll
            for (int nh = 0; nh < 2; ++nh)
                sa[Ti][nh] = __builtin_amdgcn_mfma_f32_16x16x32_f16(kf0[Ti], qf[nh][0],
                                                                    xmv[nh], 0, 0, 0);
#pragma unroll
        for (int Ti = 0; Ti < 2; ++Ti)
#pragma unroll
            for (int nh = 0; nh < 2; ++nh)
                sa[Ti][nh] = __builtin_amdgcn_mfma_f32_16x16x32_f16(kf1[Ti], qf[nh][1],
                                                                    sa[Ti][nh], 0, 0, 0);
        __builtin_amdgcn_s_setprio(0);
        // V fragment: single b128 (pre-permuted vth), chunk = frag ^ sw
        half8 vf[4];
#pragma unroll
        for (int di = 0; di < 4; ++di)
            vf[di] = *(const half8*)&VTs[((di * 16 + l15) << 6) +
                                         ((((kg << 2) + quad) ^ sw) << 3)];
#pragma unroll
        for (int nh = 0; nh < 2; ++nh) {
            half2v p2m[4];
#pragma unroll
            for (int m = 0; m < 4; ++m) {
                int Ti = m >> 1;
                int r0 = (m & 1) * 2;
                half2v x2 = cvt_pk(sa[Ti][nh][r0], sa[Ti][nh][r0 + 1]);
                half2v hp = __builtin_elementwise_fma(x2, cA, cB);
                hp = __builtin_elementwise_fma(x2, hp, cC);
                hp = __builtin_elementwise_fma(x2, hp, cD);
                half2v p2 = rcp2(hp);
                rsum[nh] = dot2acc(p2, rsum[nh]);
                p2m[m] = p2;
            }
            half8 pb = from4(p2m[0], p2m[1], p2m[2], p2m[3]);
            __builtin_amdgcn_s_setprio(1);
#pragma unroll
            for (int di = 0; di < 4; ++di)
                oacc[di][nh] = __builtin_amdgcn_mfma_f32_16x16x32_f16(vf[di], pb,
                                                                      oacc[di][nh], 0, 0, 0);
            __builtin_amdgcn_s_setprio(0);
        }
    };

    // prologue: tile 0 -> buf0
    gl_lds16(K0, &SM[t * 8]);
    gl_lds16(K0 + 2048, &SM[2048 + t * 8]);
    gl_lds16(V0, &SM[8192 + t * 8]);
    gl_lds16(V0 + 65536, &SM[8192 + 2048 + t * 8]);
    __syncthreads();

    {
        const _Float16* sK = K0 + 4096;   // tile 1 (K tile stride 64rows*64 = 4096)
        const _Float16* sV = V0 + 64;     // tile 1 (V tile stride 64 halfs)
        for (int i = 0; i < 16; ++i) {
            // stage tile 2i+1 -> buf1; compute tile 2i (buf0)
            gl_lds16(sK, &SM[4096 + t * 8]);
            gl_lds16(sK + 2048, &SM[4096 + 2048 + t * 8]);
            gl_lds16(sV, &SM[12288 + t * 8]);
            gl_lds16(sV + 65536, &SM[12288 + 2048 + t * 8]);
            sK += 4096; sV += 64;
            tile_step(&SM[0], &SM[8192]);
            __syncthreads();
            // stage tile 2i+2 -> buf0; compute tile 2i+1 (buf1)
            if (i < 15) {
                gl_lds16(sK, &SM[t * 8]);
                gl_lds16(sK + 2048, &SM[2048 + t * 8]);
                gl_lds16(sV, &SM[8192 + t * 8]);
                gl_lds16(sV + 65536, &SM[8192 + 2048 + t * 8]);
                sK += 4096; sV += 64;
            }
            tile_step(&SM[4096], &SM[12288]);
            __syncthreads();
        }
    }

#pragma unroll
    for (int nh = 0; nh < 2; ++nh) {
        rsum[nh] += __shfl_xor(rsum[nh], 16, 64);
        rsum[nh] += __shfl_xor(rsum[nh], 32, 64);
    }

    // ---- cross-wave (kg) combine: O partials + rsum, once per block ----------
    // EXO: 4096 floats (16KB) at SM[0]; EXS: 64 floats at byte 16384;
    // Os: 64x72 halfs at SM+8320. Loop ended with barrier.
    float* EXO = (float*)SM;
    float* EXS = (float*)(SM + 8192);
    _Float16* Os = SM + 8320;
    if (kg) {
#pragma unroll
        for (int nh = 0; nh < 2; ++nh)
#pragma unroll
            for (int di = 0; di < 4; ++di)
                *(floatx4*)&EXO[(((((qg * 2 + nh) * 4 + di) * 4 + quad) * 16) + l15) * 4] =
                    oacc[di][nh];
        if (quad == 0) {
#pragma unroll
            for (int nh = 0; nh < 2; ++nh)
                EXS[(qg * 2 + nh) * 16 + l15] = rsum[nh];
        }
    }
    __syncthreads();
    if (!kg) {
        float inv[2];
#pragma unroll
        for (int nh = 0; nh < 2; ++nh)
            inv[nh] = 1.0f / (rsum[nh] + EXS[(qg * 2 + nh) * 16 + l15]);
#pragma unroll
        for (int nh = 0; nh < 2; ++nh)
#pragma unroll
            for (int di = 0; di < 4; ++di) {
                floatx4 part = *(const floatx4*)
                    &EXO[(((((qg * 2 + nh) * 4 + di) * 4 + quad) * 16) + l15) * 4];
                half4 hv;
#pragma unroll
                for (int r = 0; r < 4; ++r)
                    hv[r] = (_Float16)((oacc[di][nh][r] + part[r]) * inv[nh]);
                *(half4*)&Os[(qg * 32 + nh * 16 + l15) * 72 + di * 16 + quad * 4] = hv;
            }
    }
    __syncthreads();
    // coalesced global write: 64 rows x 64 cols, 512 chunks of 16B, 2 per thread
    _Float16* Op = out + (size_t)(b * 2048 + q0) * 1024 + h * 64;
#pragma unroll
    for (int it = 0; it < 2; ++it) {
        int cc = it * 256 + t;
        int r = cc >> 3, c8 = cc & 7;
        *(half8*)&Op[(size_t)r * 1024 + c8 * 8] = *(const half8*)&Os[r * 72 + c8 * 8];
    }
}

// ---------------- launch ---------------------------------------------------------
extern "C" void kernel_launch(void* const* d_in, const int* in_sizes, int n_in,
                              void* d_out, int out_size, void* d_ws, size_t ws_size,
                              hipStream_t stream) {
    const float* x_f = (const float*)d_in[0];     // [2,2048,1024] fp32
    const float* wqkv_f = (const float*)d_in[1];  // [3072,1024] fp32
    const float* wout_f = (const float*)d_in[2];  // [1024,1024] fp32
    const float* bias_f = (const float*)d_in[3];  // [1024] fp32

    // workspace: 38 MB, with aliasing (aoh reuses xh; woh reuses wqh).
    // ORDERING CONSTRAINT: woh is written only AFTER gemm_qkv consumes wqh.
    char* ws = (char*)d_ws;
    _Float16* xh = (_Float16*)(ws);                   // [4096][1024] f16, 8 MB
    _Float16* aoh = xh;                               // alias: live after gemm_qkv
    _Float16* wqh = (_Float16*)(ws + 8388608);        // [3072][1024] f16, 6 MB
    _Float16* woh = wqh;                              // alias: live after gemm_qkv
    _Float16* qh = (_Float16*)(ws + 14680064);        // [32][2048][64] f16, 8 MB
    _Float16* kh = (_Float16*)(ws + 23068672);        // [32][2048][64] f16, 8 MB
    _Float16* vth = (_Float16*)(ws + 31457280);       // [32][64][2048] f16, 8 MB (key-permuted)

    cvt_xw<<<7168, 256, 0, stream>>>((const floatx4*)x_f, (const floatx4*)wqkv_f,
                                     (half4*)xh, (half4*)wqh);
    gemm_qkv<<<dim3(24, 32), 256, 0, stream>>>(xh, wqh, qh, kh, vth);
    cvt_f32_f16<<<1024, 256, 0, stream>>>((const floatx4*)wout_f, (half4*)woh, 262144);
    attn_kernel<<<dim3(32, 32), 256, 0, stream>>>(qh, kh, vth, aoh);
    gemm_out<<<dim3(8, 64), 256, 0, stream>>>(aoh, woh, (float*)d_out, bias_f);
}

// Round 9
// 200.270 us; speedup vs baseline: 1.3179x; 1.0190x over previous
//
#include <hip/hip_runtime.h>

typedef _Float16 half8 __attribute__((ext_vector_type(8)));
typedef _Float16 half4 __attribute__((ext_vector_type(4)));
typedef _Float16 half2v __attribute__((ext_vector_type(2)));
typedef float floatx4 __attribute__((ext_vector_type(4)));
typedef unsigned int uint2v __attribute__((ext_vector_type(2)));
typedef unsigned int uint4v __attribute__((ext_vector_type(4)));

__device__ __forceinline__ void gl_lds16(const _Float16* g, _Float16* l) {
    __builtin_amdgcn_global_load_lds(
        (const __attribute__((address_space(1))) void*)g,
        (__attribute__((address_space(3))) void*)l, 16, 0, 0);
}

__device__ __forceinline__ half2v cvt_pk(float a, float b) {
    return __builtin_bit_cast(half2v, __builtin_amdgcn_cvt_pkrtz(a, b));
}

__device__ __forceinline__ half2v rcp2(half2v d) {
#if __has_builtin(__builtin_amdgcn_rcph)
    half2v r;
    r[0] = __builtin_amdgcn_rcph(d[0]);
    r[1] = __builtin_amdgcn_rcph(d[1]);
    return r;
#else
    half2v r;
    r[0] = (_Float16)__builtin_amdgcn_rcpf((float)d[0]);
    r[1] = (_Float16)__builtin_amdgcn_rcpf((float)d[1]);
    return r;
#endif
}

__device__ __forceinline__ float dot2acc(half2v a, float acc) {
#if __has_builtin(__builtin_amdgcn_fdot2)
    const half2v one = {(_Float16)1.0f, (_Float16)1.0f};
    return __builtin_amdgcn_fdot2(a, one, acc, false);
#else
    return acc + (float)a[0] + (float)a[1];
#endif
}

// concat 4 packed half2 (each one dword) into a half8 — no element inserts
__device__ __forceinline__ half8 from4(half2v a, half2v b, half2v c, half2v d) {
    uint4v u = {__builtin_bit_cast(unsigned int, a), __builtin_bit_cast(unsigned int, b),
                __builtin_bit_cast(unsigned int, c), __builtin_bit_cast(unsigned int, d)};
    return __builtin_bit_cast(half8, u);
}

// concat two half4 (two dword-pairs) into a half8 — no element inserts
__device__ __forceinline__ half8 from_lohi(half4 lo, half4 hi) {
    uint2v l = __builtin_bit_cast(uint2v, lo);
    uint2v h = __builtin_bit_cast(uint2v, hi);
    uint4v u = {l[0], l[1], h[0], h[1]};
    return __builtin_bit_cast(half8, u);
}

// ---------------- fp32 -> fp16 convert: x and w_qkv fused (runs BEFORE gemm_qkv) -
__global__ __launch_bounds__(256) void cvt_xw(const floatx4* __restrict__ x,
                                              const floatx4* __restrict__ wq,
                                              half4* __restrict__ xh,
                                              half4* __restrict__ wqh) {
    int i = blockIdx.x * 256 + threadIdx.x;   // 0..1835007
    floatx4 v;
    half4 h;
    if (i < 1048576) {
        v = x[i];
#pragma unroll
        for (int j = 0; j < 4; ++j) h[j] = (_Float16)v[j];
        xh[i] = h;
    } else {
        int j4 = i - 1048576;
        v = wq[j4];
#pragma unroll
        for (int j = 0; j < 4; ++j) h[j] = (_Float16)v[j];
        wqh[j4] = h;
    }
}

// wout cvt — MUST run after gemm_qkv (woh aliases wqh)
__global__ __launch_bounds__(256) void cvt_f32_f16(const floatx4* __restrict__ in,
                                                   half4* __restrict__ out, int n4) {
    int i = blockIdx.x * 256 + threadIdx.x;
    if (i >= n4) return;
    floatx4 v = in[i];
    half4 h;
#pragma unroll
    for (int j = 0; j < 4; ++j) h[j] = (_Float16)v[j];
    out[i] = h;
}

// ---------------- GEMM1: qkv = xh @ wqh^T -> head-major q/k/vt (fp16 in/out) -----
// M=4096, N=3072, K=1024. 128x128 tile, 256 thr, DMA staging.
// R9: BK 32 -> 64 — halves the barrier/drain count (the 2-phase stall, m233);
// tiles stored XOR-chunk-swizzled (source chunk ^= row&7, same XOR on reads —
// attn-proven both-sides scheme) to kill the 16-way conflict a 128B row stride
// would otherwise create. Per-kk work identical to two BK=32 steps.
// vth is stored KEY-PERMUTED within each 64-key tile:
//   stored position p = c*32 + q*8 + j  holds key  c*32 + (j>>2)*16 + q*4 + (j&3)
// so attn's PV fragment (kg=c, quad=q) is one contiguous 16B ds_read_b128.
__global__ __launch_bounds__(256) void gemm_qkv(const _Float16* __restrict__ A,
                                                const _Float16* __restrict__ B,
                                                _Float16* __restrict__ qh,
                                                _Float16* __restrict__ kh,
                                                _Float16* __restrict__ vth) {
    const int K = 1024;
    __shared__ _Float16 SH[16384];      // As 128x64 (16KB) | Bs 128x64 (16KB)
    _Float16* As = SH;
    _Float16* Bs = SH + 8192;
    const int t = threadIdx.x;
    const int lane = t & 63, w = t >> 6;
    const int l15 = lane & 15, quad = lane >> 4;
    const int sw = l15 & 7;             // read-side swizzle key (row&7)
    const int wm = w >> 1, wn = w & 1;
    const int m0 = blockIdx.y * 128, n0 = blockIdx.x * 128;

    floatx4 acc[4][4];
    const floatx4 zf = {0.f, 0.f, 0.f, 0.f};
#pragma unroll
    for (int i = 0; i < 4; ++i)
#pragma unroll
        for (int j = 0; j < 4; ++j) acc[i][j] = zf;

    for (int kt = 0; kt < K; kt += 64) {
        __syncthreads();
#pragma unroll
        for (int j = 0; j < 4; ++j) {   // 1024 chunks of 16B per matrix
            int cc = j * 256 + t;
            int row = cc >> 3;
            int kcs = (cc & 7) ^ (row & 7);   // pre-swizzled source chunk
            gl_lds16(&A[(size_t)(m0 + row) * K + kt + kcs * 8], &As[cc * 8]);
            gl_lds16(&B[(size_t)(n0 + row) * K + kt + kcs * 8], &Bs[cc * 8]);
        }
        __syncthreads();
#pragma unroll
        for (int kk = 0; kk < 2; ++kk) {
            half8 af[4], bfr[4];
#pragma unroll
            for (int i = 0; i < 4; ++i)
                af[i] = *(const half8*)&As[((wm * 64 + i * 16 + l15) << 6) +
                                           ((((kk << 2) + quad) ^ sw) << 3)];
#pragma unroll
            for (int i = 0; i < 4; ++i)
                bfr[i] = *(const half8*)&Bs[((wn * 64 + i * 16 + l15) << 6) +
                                            ((((kk << 2) + quad) ^ sw) << 3)];
#pragma unroll
            for (int mi = 0; mi < 4; ++mi)
#pragma unroll
                for (int ni = 0; ni < 4; ++ni)
                    acc[mi][ni] = __builtin_amdgcn_mfma_f32_16x16x32_f16(af[mi], bfr[ni],
                                                                         acc[mi][ni], 0, 0, 0);
        }
    }

    // ---- epilogue: two 128x64 col-halves staged through LDS, coalesced writes ----
    const int b = m0 >> 11, s0 = m0 & 2047;
#pragma unroll
    for (int hf = 0; hf < 2; ++hf) {
        __syncthreads();
        if (wn == hf) {
#pragma unroll
            for (int mi = 0; mi < 4; ++mi)
#pragma unroll
                for (int ni = 0; ni < 4; ++ni)
#pragma unroll
                    for (int r = 0; r < 4; ++r)
                        SH[(wm * 64 + mi * 16 + quad * 4 + r) * 68 + ni * 16 + l15] =
                            (_Float16)acc[mi][ni][r];
        }
        __syncthreads();
        const int cbase = n0 + hf * 64;
        if (n0 < 2048) {
            const int hh = (cbase & 1023) >> 6;
            _Float16* dst = (n0 < 1024 ? qh : kh) + (size_t)((b << 4) | hh) * 131072;
#pragma unroll
            for (int it = 0; it < 4; ++it) {
                int cc = it * 256 + t;
                int r = cc >> 3, c8 = cc & 7;
                half4 lo = *(const half4*)&SH[r * 68 + c8 * 8];
                half4 hi = *(const half4*)&SH[r * 68 + c8 * 8 + 4];
                *(half8*)&dst[(size_t)(s0 + r) * 64 + c8 * 8] = from_lohi(lo, hi);
            }
        } else {
            const int hh = (cbase - 2048) >> 6;
            _Float16* dst = vth + (size_t)((b << 4) | hh) * 131072;
#pragma unroll
            for (int it = 0; it < 4; ++it) {
                int cc = it * 256 + t;
                int d = cc >> 4, s8 = cc & 15;
                // key-permuted gather: stored p=(s8&7)*8+j <- key base+(j>>2)*16+(j&3)
                int sq = s8 & 7;
                int base = (s8 >> 3) * 64 + (sq >> 2) * 32 + (sq & 3) * 4;
                half8 v;
#pragma unroll
                for (int j = 0; j < 8; ++j)
                    v[j] = SH[(base + (j >> 2) * 16 + (j & 3)) * 68 + d];
                *(half8*)&dst[(size_t)d * 2048 + s0 + s8 * 8] = v;
            }
        }
    }
}

// ---------------- GEMM2: out = aoh @ woh^T + b_out -> fp32 -----------------------
// M=4096, N=1024, K=1024. 64x128 tile, 256 thr, DMA staging.
// R9: BK 32 -> 64 (halve barriers) + XOR-chunk swizzle, same as gemm_qkv.
__global__ __launch_bounds__(256) void gemm_out(const _Float16* __restrict__ A,
                                                const _Float16* __restrict__ B,
                                                float* __restrict__ C,
                                                const float* __restrict__ bias) {
    const int K = 1024, N = 1024;
    __shared__ _Float16 SH[12288];      // As 64x64 (8KB) | Bs 128x64 (16KB)
    _Float16* As = SH;
    _Float16* Bs = SH + 4096;
    const int t = threadIdx.x;
    const int lane = t & 63, w = t >> 6;
    const int l15 = lane & 15, quad = lane >> 4;
    const int sw = l15 & 7;
    const int wm = w >> 1, wn = w & 1;
    const int m0 = blockIdx.y * 64, n0 = blockIdx.x * 128;

    floatx4 acc[2][4];
    const floatx4 zf = {0.f, 0.f, 0.f, 0.f};
#pragma unroll
    for (int i = 0; i < 2; ++i)
#pragma unroll
        for (int j = 0; j < 4; ++j) acc[i][j] = zf;

    for (int kt = 0; kt < K; kt += 64) {
        __syncthreads();
#pragma unroll
        for (int j = 0; j < 2; ++j) {   // A: 512 chunks of 16B
            int cc = j * 256 + t;
            int row = cc >> 3;
            int kcs = (cc & 7) ^ (row & 7);
            gl_lds16(&A[(size_t)(m0 + row) * K + kt + kcs * 8], &As[cc * 8]);
        }
#pragma unroll
        for (int j = 0; j < 4; ++j) {   // B: 1024 chunks of 16B
            int cc = j * 256 + t;
            int row = cc >> 3;
            int kcs = (cc & 7) ^ (row & 7);
            gl_lds16(&B[(size_t)(n0 + row) * K + kt + kcs * 8], &Bs[cc * 8]);
        }
        __syncthreads();
#pragma unroll
        for (int kk = 0; kk < 2; ++kk) {
            half8 af[2], bfr[4];
#pragma unroll
            for (int i = 0; i < 2; ++i)
                af[i] = *(const half8*)&As[((wm * 32 + i * 16 + l15) << 6) +
                                           ((((kk << 2) + quad) ^ sw) << 3)];
#pragma unroll
            for (int i = 0; i < 4; ++i)
                bfr[i] = *(const half8*)&Bs[((wn * 64 + i * 16 + l15) << 6) +
                                            ((((kk << 2) + quad) ^ sw) << 3)];
#pragma unroll
            for (int mi = 0; mi < 2; ++mi)
#pragma unroll
                for (int ni = 0; ni < 4; ++ni)
                    acc[mi][ni] = __builtin_amdgcn_mfma_f32_16x16x32_f16(af[mi], bfr[ni],
                                                                         acc[mi][ni], 0, 0, 0);
        }
    }

#pragma unroll
    for (int mi = 0; mi < 2; ++mi) {
#pragma unroll
        for (int ni = 0; ni < 4; ++ni) {
            int col = n0 + wn * 64 + ni * 16 + l15;
            float bv = bias[col];
#pragma unroll
            for (int r = 0; r < 4; ++r) {
                int row = m0 + wm * 32 + mi * 16 + quad * 4 + r;
                C[(size_t)row * N + col] = acc[mi][ni][r] + bv;
            }
        }
    }
}

// ---------------- fused two-pass stablemax attention (split-K, 4 waves) ----------
// R9: UNCHANGED from R8 (65.1us measured; conflicts 98K, FETCH 12MB) — serves as
// the control for this round's GEMM changes. Structure: split-K (qg,kg) waves,
// pass-1 128-key dbuf tiles, pass-2 2-step-unrolled 64-key K+V dbuf, XOR-chunk
// swizzle, key-permuted vth (single b128 V reads), XCD head-grouped grid,
// xm via MFMA C-in, setprio, cross-wave combine.
__global__ __launch_bounds__(256, 4) void attn_kernel(const _Float16* __restrict__ qh,
                                                      const _Float16* __restrict__ kh,
                                                      const _Float16* __restrict__ vth,
                                                      _Float16* __restrict__ out) {
    // pass 1: K128 dbuf = SM[0..8191] | SM[8192..16383]
    // pass 2: K buf0 SM[0] K buf1 SM[4096] | V buf0 SM[8192] V buf1 SM[12288]
    // epilogue reuse: EXO 16KB @SM[0], EXS @byte16384, Os @SM+8320
    __shared__ _Float16 SM[16384];

    const int t = threadIdx.x;
    const int lane = t & 63, w = t >> 6;          // 4 waves
    const int l15 = lane & 15, quad = lane >> 4;
    const int sw = l15 & 7;                       // read-side swizzle key (row&7)
    const int qg = w >> 1, kg = w & 1;
    const int bh = blockIdx.x;                    // fastest dim -> XCD head groups
    const int q0 = blockIdx.y * 64;
    const int b = bh >> 4, h = bh & 15;

    const _Float16* Qp = qh + (size_t)bh * 131072 + q0 * 64;
    const _Float16* Kp = kh + (size_t)bh * 131072;
    const _Float16* VTp = vth + (size_t)bh * 131072;

    // staging lane bases: dest slot (row, cs=t&7) holds global chunk cg=cs^(row&7)
    const int row0 = t >> 3, cg0 = (t & 7) ^ (row0 & 7);
    const _Float16* K0 = &Kp[(size_t)row0 * 64 + cg0 * 8];     // +2048/32rows, +4096/tile64
    const _Float16* V0 = &VTp[(size_t)row0 * 2048 + cg0 * 8];  // +65536/32rows, +64/tile64

    const floatx4 zf = {0.f, 0.f, 0.f, 0.f};

    half8 qf[2][2];   // [nh][kk], pre-scaled by 0.125
#pragma unroll
    for (int nh = 0; nh < 2; ++nh)
#pragma unroll
        for (int kk = 0; kk < 2; ++kk) {
            half8 q = *(const half8*)&Qp[(qg * 32 + nh * 16 + l15) * 64 + kk * 32 + quad * 8];
#pragma unroll
            for (int j = 0; j < 8; ++j) q[j] = q[j] * (_Float16)0.125f;
            qf[nh][kk] = q;
        }

    // ---------------- pass 1: row max, 128-key tiles, 16 steps -----------------
    float rmax[2] = {-1.0e30f, -1.0e30f};
#pragma unroll
    for (int s = 0; s < 4; ++s)
        gl_lds16(K0 + s * 2048, &SM[s * 2048 + t * 8]);
    __syncthreads();
    {
        const _Float16* sKp = K0 + 8192;   // tile 1
        for (int i = 0, cur = 0; i < 16; ++i, cur ^= 1) {
            if (i < 15) {
                _Float16* kd = cur ? &SM[0] : &SM[8192];
#pragma unroll
                for (int s = 0; s < 4; ++s)
                    gl_lds16(sKp + s * 2048, kd + s * 2048 + t * 8);
                sKp += 8192;
            }
            const _Float16* Ks = cur ? &SM[8192] : &SM[0];
            half8 kf0[4], kf1[4];
#pragma unroll
            for (int Ti = 0; Ti < 4; ++Ti) {
                const int rb = ((kg * 4 + Ti) * 16 + l15) << 6;
                kf0[Ti] = *(const half8*)&Ks[rb + ((quad ^ sw) << 3)];
                kf1[Ti] = *(const half8*)&Ks[rb + (((4 + quad) ^ sw) << 3)];
            }
            floatx4 sa[4][2];
            __builtin_amdgcn_s_setprio(1);
#pragma unroll
            for (int Ti = 0; Ti < 4; ++Ti)
#pragma unroll
                for (int nh = 0; nh < 2; ++nh)
                    sa[Ti][nh] = __builtin_amdgcn_mfma_f32_16x16x32_f16(kf0[Ti], qf[nh][0],
                                                                        zf, 0, 0, 0);
#pragma unroll
            for (int Ti = 0; Ti < 4; ++Ti)
#pragma unroll
                for (int nh = 0; nh < 2; ++nh)
                    sa[Ti][nh] = __builtin_amdgcn_mfma_f32_16x16x32_f16(kf1[Ti], qf[nh][1],
                                                                        sa[Ti][nh], 0, 0, 0);
            __builtin_amdgcn_s_setprio(0);
#pragma unroll
            for (int Ti = 0; Ti < 4; ++Ti)
#pragma unroll
                for (int nh = 0; nh < 2; ++nh)
#pragma unroll
                    for (int r = 0; r < 4; ++r)
                        rmax[nh] = fmaxf(rmax[nh], sa[Ti][nh][r]);
            __syncthreads();
        }
    }
#pragma unroll
    for (int nh = 0; nh < 2; ++nh) {
        rmax[nh] = fmaxf(rmax[nh], __shfl_xor(rmax[nh], 16, 64));
        rmax[nh] = fmaxf(rmax[nh], __shfl_xor(rmax[nh], 32, 64));
    }
    // cross-wave (kg) max combine via LDS floats (loop ended with barrier)
    {
        float* EXM = (float*)SM;
        if (quad == 0) {
#pragma unroll
            for (int nh = 0; nh < 2; ++nh)
                EXM[((qg * 2 + nh) * 2 + kg) * 16 + l15] = rmax[nh];
        }
        __syncthreads();
#pragma unroll
        for (int nh = 0; nh < 2; ++nh)
            rmax[nh] = fmaxf(EXM[((qg * 2 + nh) * 2 + 0) * 16 + l15],
                             EXM[((qg * 2 + nh) * 2 + 1) * 16 + l15]);
        __syncthreads();   // EX reads done before pass-2 DMA overwrites
    }
    const floatx4 xmv[2] = {{-rmax[0], -rmax[0], -rmax[0], -rmax[0]},
                            {-rmax[1], -rmax[1], -rmax[1], -rmax[1]}};

    // ---------------- pass 2: p = s3(x); Sum p; P·V ---------------------------
    const half2v cA = {(_Float16)(-1.0f / 6.0f), (_Float16)(-1.0f / 6.0f)};
    const half2v cB = {(_Float16)0.5f, (_Float16)0.5f};
    const half2v cC = {(_Float16)-1.0f, (_Float16)-1.0f};
    const half2v cD = {(_Float16)1.0f, (_Float16)1.0f};

    float rsum[2] = {0.f, 0.f};
    floatx4 oacc[4][2];
#pragma unroll
    for (int i = 0; i < 4; ++i) { oacc[i][0] = zf; oacc[i][1] = zf; }

    // one 64-key tile: QK^T (sa from xmv C-in) -> s3 poly -> PV
    auto tile_step = [&](const _Float16* Ks, const _Float16* VTs) {
        half8 kf0[2], kf1[2];
#pragma unroll
        for (int Ti = 0; Ti < 2; ++Ti) {
            const int rb = ((kg * 2 + Ti) * 16 + l15) << 6;
            kf0[Ti] = *(const half8*)&Ks[rb + ((quad ^ sw) << 3)];
            kf1[Ti] = *(const half8*)&Ks[rb + (((4 + quad) ^ sw) << 3)];
        }
        floatx4 sa[2][2];
        __builtin_amdgcn_s_setprio(1);
#pragma unroll
        for (int Ti = 0; Ti < 2; ++Ti)
#pragma unroll
            for (int nh = 0; nh < 2; ++nh)
                sa[Ti][nh] = __builtin_amdgcn_mfma_f32_16x16x32_f16(kf0[Ti], qf[nh][0],
                                                                    xmv[nh], 0, 0, 0);
#pragma unroll
        for (int Ti = 0; Ti < 2; ++Ti)
#pragma unroll
            for (int nh = 0; nh < 2; ++nh)
                sa[Ti][nh] = __builtin_amdgcn_mfma_f32_16x16x32_f16(kf1[Ti], qf[nh][1],
                                                                    sa[Ti][nh], 0, 0, 0);
        __builtin_amdgcn_s_setprio(0);
        // V fragment: single b128 (pre-permuted vth), chunk = frag ^ sw
        half8 vf[4];
#pragma unroll
        for (int di = 0; di < 4; ++di)
            vf[di] = *(const half8*)&VTs[((di * 16 + l15) << 6) +
                                         ((((kg << 2) + quad) ^ sw) << 3)];
#pragma unroll
        for (int nh = 0; nh < 2; ++nh) {
            half2v p2m[4];
#pragma unroll
            for (int m = 0; m < 4; ++m) {
                int Ti = m >> 1;
                int r0 = (m & 1) * 2;
                half2v x2 = cvt_pk(sa[Ti][nh][r0], sa[Ti][nh][r0 + 1]);
                half2v hp = __builtin_elementwise_fma(x2, cA, cB);
                hp = __builtin_elementwise_fma(x2, hp, cC);
                hp = __builtin_elementwise_fma(x2, hp, cD);
                half2v p2 = rcp2(hp);
                rsum[nh] = dot2acc(p2, rsum[nh]);
                p2m[m] = p2;
            }
            half8 pb = from4(p2m[0], p2m[1], p2m[2], p2m[3]);
            __builtin_amdgcn_s_setprio(1);
#pragma unroll
            for (int di = 0; di < 4; ++di)
                oacc[di][nh] = __builtin_amdgcn_mfma_f32_16x16x32_f16(vf[di], pb,
                                                                      oacc[di][nh], 0, 0, 0);
            __builtin_amdgcn_s_setprio(0);
        }
    };

    // prologue: tile 0 -> buf0
    gl_lds16(K0, &SM[t * 8]);
    gl_lds16(K0 + 2048, &SM[2048 + t * 8]);
    gl_lds16(V0, &SM[8192 + t * 8]);
    gl_lds16(V0 + 65536, &SM[8192 + 2048 + t * 8]);
    __syncthreads();

    {
        const _Float16* sK = K0 + 4096;   // tile 1 (K tile stride 64rows*64 = 4096)
        const _Float16* sV = V0 + 64;     // tile 1 (V tile stride 64 halfs)
        for (int i = 0; i < 16; ++i) {
            // stage tile 2i+1 -> buf1; compute tile 2i (buf0)
            gl_lds16(sK, &SM[4096 + t * 8]);
            gl_lds16(sK + 2048, &SM[4096 + 2048 + t * 8]);
            gl_lds16(sV, &SM[12288 + t * 8]);
            gl_lds16(sV + 65536, &SM[12288 + 2048 + t * 8]);
            sK += 4096; sV += 64;
            tile_step(&SM[0], &SM[8192]);
            __syncthreads();
            // stage tile 2i+2 -> buf0; compute tile 2i+1 (buf1)
            if (i < 15) {
                gl_lds16(sK, &SM[t * 8]);
                gl_lds16(sK + 2048, &SM[2048 + t * 8]);
                gl_lds16(sV, &SM[8192 + t * 8]);
                gl_lds16(sV + 65536, &SM[8192 + 2048 + t * 8]);
                sK += 4096; sV += 64;
            }
            tile_step(&SM[4096], &SM[12288]);
            __syncthreads();
        }
    }

#pragma unroll
    for (int nh = 0; nh < 2; ++nh) {
        rsum[nh] += __shfl_xor(rsum[nh], 16, 64);
        rsum[nh] += __shfl_xor(rsum[nh], 32, 64);
    }

    // ---- cross-wave (kg) combine: O partials + rsum, once per block ----------
    // EXO: 4096 floats (16KB) at SM[0]; EXS: 64 floats at byte 16384;
    // Os: 64x72 halfs at SM+8320. Loop ended with barrier.
    float* EXO = (float*)SM;
    float* EXS = (float*)(SM + 8192);
    _Float16* Os = SM + 8320;
    if (kg) {
#pragma unroll
        for (int nh = 0; nh < 2; ++nh)
#pragma unroll
            for (int di = 0; di < 4; ++di)
                *(floatx4*)&EXO[(((((qg * 2 + nh) * 4 + di) * 4 + quad) * 16) + l15) * 4] =
                    oacc[di][nh];
        if (quad == 0) {
#pragma unroll
            for (int nh = 0; nh < 2; ++nh)
                EXS[(qg * 2 + nh) * 16 + l15] = rsum[nh];
        }
    }
    __syncthreads();
    if (!kg) {
        float inv[2];
#pragma unroll
        for (int nh = 0; nh < 2; ++nh)
            inv[nh] = 1.0f / (rsum[nh] + EXS[(qg * 2 + nh) * 16 + l15]);
#pragma unroll
        for (int nh = 0; nh < 2; ++nh)
#pragma unroll
            for (int di = 0; di < 4; ++di) {
                floatx4 part = *(const floatx4*)
                    &EXO[(((((qg * 2 + nh) * 4 + di) * 4 + quad) * 16) + l15) * 4];
                half4 hv;
#pragma unroll
                for (int r = 0; r < 4; ++r)
                    hv[r] = (_Float16)((oacc[di][nh][r] + part[r]) * inv[nh]);
                *(half4*)&Os[(qg * 32 + nh * 16 + l15) * 72 + di * 16 + quad * 4] = hv;
            }
    }
    __syncthreads();
    // coalesced global write: 64 rows x 64 cols, 512 chunks of 16B, 2 per thread
    _Float16* Op = out + (size_t)(b * 2048 + q0) * 1024 + h * 64;
#pragma unroll
    for (int it = 0; it < 2; ++it) {
        int cc = it * 256 + t;
        int r = cc >> 3, c8 = cc & 7;
        *(half8*)&Op[(size_t)r * 1024 + c8 * 8] = *(const half8*)&Os[r * 72 + c8 * 8];
    }
}

// ---------------- launch ---------------------------------------------------------
extern "C" void kernel_launch(void* const* d_in, const int* in_sizes, int n_in,
                              void* d_out, int out_size, void* d_ws, size_t ws_size,
                              hipStream_t stream) {
    const float* x_f = (const float*)d_in[0];     // [2,2048,1024] fp32
    const float* wqkv_f = (const float*)d_in[1];  // [3072,1024] fp32
    const float* wout_f = (const float*)d_in[2];  // [1024,1024] fp32
    const float* bias_f = (const float*)d_in[3];  // [1024] fp32

    // workspace: 38 MB, with aliasing (aoh reuses xh; woh reuses wqh).
    // ORDERING CONSTRAINT: woh is written only AFTER gemm_qkv consumes wqh.
    char* ws = (char*)d_ws;
    _Float16* xh = (_Float16*)(ws);                   // [4096][1024] f16, 8 MB
    _Float16* aoh = xh;                               // alias: live after gemm_qkv
    _Float16* wqh = (_Float16*)(ws + 8388608);        // [3072][1024] f16, 6 MB
    _Float16* woh = wqh;                              // alias: live after gemm_qkv
    _Float16* qh = (_Float16*)(ws + 14680064);        // [32][2048][64] f16, 8 MB
    _Float16* kh = (_Float16*)(ws + 23068672);        // [32][2048][64] f16, 8 MB
    _Float16* vth = (_Float16*)(ws + 31457280);       // [32][64][2048] f16, 8 MB (key-permuted)

    cvt_xw<<<7168, 256, 0, stream>>>((const floatx4*)x_f, (const floatx4*)wqkv_f,
                                     (half4*)xh, (half4*)wqh);
    gemm_qkv<<<dim3(24, 32), 256, 0, stream>>>(xh, wqh, qh, kh, vth);
    cvt_f32_f16<<<1024, 256, 0, stream>>>((const floatx4*)wout_f, (half4*)woh, 262144);
    attn_kernel<<<dim3(32, 32), 256, 0, stream>>>(qh, kh, vth, aoh);
    gemm_out<<<dim3(8, 64), 256, 0, stream>>>(aoh, woh, (float*)d_out, bias_f);
}